// Round 7
// baseline (191.039 us; speedup 1.0000x reference)
//
#include <hip/hip_runtime.h>

#define B_  2
#define T_  2048
#define C_  1024
#define H_  16
#define HS_ 64
#define M_  4096
#define N_  1024
#define K_  1024

typedef float floatx4 __attribute__((ext_vector_type(4)));
typedef short bf16x8  __attribute__((ext_vector_type(8)));

__device__ __forceinline__ float bf2f(unsigned short u) {
    return __uint_as_float(((unsigned int)u) << 16);
}
__device__ __forceinline__ unsigned short f2bf(float f) {
    unsigned int u = __float_as_uint(f);
    return (unsigned short)((u + 0x7fffu + ((u >> 16) & 1u)) >> 16);
}
__device__ __forceinline__ unsigned int pack2(float a, float b) {
    return (unsigned int)f2bf(a) | ((unsigned int)f2bf(b) << 16);
}
// truncating bf16 pair pack: one v_perm_b32
__device__ __forceinline__ unsigned int pack2t(float a, float b) {
    return __builtin_amdgcn_perm(__float_as_uint(b), __float_as_uint(a), 0x07060302u);
}
// async global->LDS, 16B per lane; lds dest = wave-uniform base + lane*16
__device__ __forceinline__ void async16(const unsigned short* g, unsigned short* l) {
    __builtin_amdgcn_global_load_lds(
        (const __attribute__((address_space(1))) unsigned int*)g,
        (__attribute__((address_space(3))) unsigned int*)l, 16, 0, 0);
}

// ---------------------------------------------------------------------------
// Prep (merged): blocks 0..4095 convert x fp32->bf16; blocks 4096..5119
// transpose+convert weights (z = (bid-4096)>>8 selects wq/wk/wv/wc).
// grid 5120, block 256.
// ---------------------------------------------------------------------------
__global__ __launch_bounds__(256) void prep_kernel(
    const float* __restrict__ x,
    const float* __restrict__ w0, const float* __restrict__ w1,
    const float* __restrict__ w2, const float* __restrict__ w3,
    unsigned short* __restrict__ xb, unsigned short* __restrict__ wTall)
{
    __shared__ float tile[64][65];
    const int bid = blockIdx.x;
    const int t = threadIdx.x;
    if (bid < 4096) {
        const size_t i = ((size_t)bid * 256 + t) * 4;
        const float4 v = *(const float4*)(x + i);
        ushort4 st;
        st.x = f2bf(v.x); st.y = f2bf(v.y); st.z = f2bf(v.z); st.w = f2bf(v.w);
        *(ushort4*)(xb + i) = st;
        return;
    }
    const int zb = bid - 4096;
    const int z = zb >> 8, rem = zb & 255;
    const float* w = (z == 0) ? w0 : (z == 1) ? w1 : (z == 2) ? w2 : w3;
    unsigned short* wT = wTall + ((size_t)z << 20);
    const int n0 = (rem & 15) * 64, k0 = (rem >> 4) * 64;

    const int r = t >> 2, cq = (t & 3) * 16;
    const float4* src = (const float4*)(w + (size_t)(k0 + r) * N_ + n0 + cq);
    const float4 v0 = src[0], v1 = src[1], v2 = src[2], v3 = src[3];
    tile[r][cq+0]=v0.x; tile[r][cq+1]=v0.y; tile[r][cq+2]=v0.z; tile[r][cq+3]=v0.w;
    tile[r][cq+4]=v1.x; tile[r][cq+5]=v1.y; tile[r][cq+6]=v1.z; tile[r][cq+7]=v1.w;
    tile[r][cq+8]=v2.x; tile[r][cq+9]=v2.y; tile[r][cq+10]=v2.z; tile[r][cq+11]=v2.w;
    tile[r][cq+12]=v3.x; tile[r][cq+13]=v3.y; tile[r][cq+14]=v3.z; tile[r][cq+15]=v3.w;
    __syncthreads();

    const int rn = t >> 2, ck = (t & 3) * 16;
    unsigned int o[8];
#pragma unroll
    for (int ii = 0; ii < 8; ii++)
        o[ii] = pack2(tile[ck + 2*ii][rn], tile[ck + 2*ii + 1][rn]);
    unsigned short* dst = wT + (size_t)(n0 + rn) * K_ + k0 + ck;
    *(uint4*)dst       = make_uint4(o[0], o[1], o[2], o[3]);
    *(uint4*)(dst + 8) = make_uint4(o[4], o[5], o[6], o[7]);
}

// ---------------------------------------------------------------------------
// Kernel 1: fused QKV GEMM + RoPE epilogue.
// Single GEMM M=4096, N=3072, 256x256 tile, BK=64, 8 waves, 8-phase schedule
// with counted vmcnt (T3+T4), LDS chunk-XOR swizzle (T2), setprio (T5).
// Tail drain: vmcnt(0) when stages are predicated off (t>=14/15).
// grid 192, block 512.
// ---------------------------------------------------------------------------
__global__ __launch_bounds__(512, 2) void qkv_gemm(
    const unsigned short* __restrict__ xb, const unsigned short* __restrict__ wT,
    const float* __restrict__ bq, const float* __restrict__ bk,
    const float* __restrict__ bv,
    unsigned short* __restrict__ qb, unsigned short* __restrict__ kb,
    unsigned short* __restrict__ vb)
{
    __shared__ unsigned short lds[65536];   // 128 KiB

    const int tid  = threadIdx.x;
    const int lane = tid & 63;
    const int wave = tid >> 6;

    // XCD-aware swizzle (192 % 8 == 0 -> simple bijective form)
    const int bid = blockIdx.x;
    const int swz = (bid & 7) * 24 + (bid >> 3);
    const int nb  = swz % 12;
    const int mb  = swz / 12;
    const int m0  = mb * 256;
    const int n0g = nb * 256;

    const int wm = wave >> 2, wn = wave & 3;       // 2 x 4 wave grid
    const int fr = lane & 15, quad = lane >> 4;

    // staging: gload g covers LDS rows [g*128, g*128+128); thread t ->
    // row g*128+(t>>2), physical chunk t&3; source chunk = phys ^ ((row>>1)&3)
    const int r_s = tid >> 2;
    const int c_s = (tid & 3) ^ ((tid >> 3) & 3);
    const unsigned short* aS0 = xb + (size_t)(m0 + r_s) * 1024 + c_s * 8;
    const unsigned short* aS1 = aS0 + (size_t)128 * 1024;
    const unsigned short* bS0 = wT + (size_t)(n0g + r_s) * 1024 + c_s * 8;
    const unsigned short* bS1 = bS0 + (size_t)128 * 1024;
    unsigned short* ldw = &lds[wave * 512];        // wave-uniform dest base

    auto stage = [&](int buf, int region, const unsigned short* s0,
                     const unsigned short* s1) {
        unsigned short* d = ldw + buf * 32768 + region * 8192;
        async16(s0, d);
        async16(s1, d + 4096);
    };

    // fragment read offsets (ushort units), swizzled
    int oA[8], oB[4];
#pragma unroll
    for (int i = 0; i < 8; i++) {
        const int r = wm * 128 + i * 16 + fr;
        oA[i] = r * 32 + ((quad ^ ((r >> 1) & 3)) << 3);
    }
#pragma unroll
    for (int j = 0; j < 4; j++) {
        const int r = wn * 64 + j * 16 + fr;
        oB[j] = r * 32 + ((quad ^ ((r >> 1) & 3)) << 3);
    }

    floatx4 acc[8][4];
#pragma unroll
    for (int i = 0; i < 8; i++)
#pragma unroll
        for (int j = 0; j < 4; j++) acc[i][j] = (floatx4){0.f, 0.f, 0.f, 0.f};

    // prologue
    stage(0, 0, aS0,      aS1);
    stage(0, 2, bS0,      bS1);
    stage(0, 1, aS0 + 32, aS1 + 32);
    stage(0, 3, bS0 + 32, bS1 + 32);
    stage(1, 0, aS0 + 64, aS1 + 64);
    stage(1, 2, bS0 + 64, bS1 + 64);
    asm volatile("s_waitcnt vmcnt(8)" ::: "memory");   // k0(0) landed
    __builtin_amdgcn_s_barrier();
    __builtin_amdgcn_sched_barrier(0);

    bf16x8 af[4], bfr[4];
#pragma unroll 2
    for (int t = 0; t < 16; ++t) {
        const int cur = t & 1, nxt = cur ^ 1;
        const unsigned short* A0 = &lds[cur * 32768];
        const unsigned short* A1 = A0 + 8192;
        const unsigned short* B0 = A0 + 16384;
        const unsigned short* B1 = A0 + 24576;
        const int k1 = (t + 1) * 64, k2 = (t + 2) * 64;

        // ---------------- phase 0: kk=0, ihalf=0 ----------------
#pragma unroll
        for (int i = 0; i < 4; i++) af[i]  = *(const bf16x8*)&A0[oA[i]];
#pragma unroll
        for (int j = 0; j < 4; j++) bfr[j] = *(const bf16x8*)&B0[oB[j]];
        if (t + 1 < 16) stage(nxt, 1, aS0 + k1 + 32, aS1 + k1 + 32);
        __builtin_amdgcn_s_barrier();
        asm volatile("s_waitcnt lgkmcnt(0)" ::: "memory");
        __builtin_amdgcn_s_setprio(1);
#pragma unroll
        for (int i = 0; i < 4; i++)
#pragma unroll
            for (int j = 0; j < 4; j++)
                acc[i][j] = __builtin_amdgcn_mfma_f32_16x16x32_bf16(
                    af[i], bfr[j], acc[i][j], 0, 0, 0);
        __builtin_amdgcn_s_setprio(0);
        __builtin_amdgcn_s_barrier();
        __builtin_amdgcn_sched_barrier(0);

        // ---------------- phase 1: kk=0, ihalf=1 ----------------
#pragma unroll
        for (int i = 0; i < 4; i++) af[i] = *(const bf16x8*)&A0[oA[4 + i]];
        if (t + 1 < 16) stage(nxt, 3, bS0 + k1 + 32, bS1 + k1 + 32);
        if (t < 15) { asm volatile("s_waitcnt vmcnt(8)" ::: "memory"); }
        else        { asm volatile("s_waitcnt vmcnt(0)" ::: "memory"); }
        __builtin_amdgcn_s_barrier();
        asm volatile("s_waitcnt lgkmcnt(0)" ::: "memory");
        __builtin_amdgcn_s_setprio(1);
#pragma unroll
        for (int i = 0; i < 4; i++)
#pragma unroll
            for (int j = 0; j < 4; j++)
                acc[4 + i][j] = __builtin_amdgcn_mfma_f32_16x16x32_bf16(
                    af[i], bfr[j], acc[4 + i][j], 0, 0, 0);
        __builtin_amdgcn_s_setprio(0);
        __builtin_amdgcn_s_barrier();
        __builtin_amdgcn_sched_barrier(0);

        // ---------------- phase 2: kk=1, ihalf=0 ----------------
#pragma unroll
        for (int i = 0; i < 4; i++) af[i]  = *(const bf16x8*)&A1[oA[i]];
#pragma unroll
        for (int j = 0; j < 4; j++) bfr[j] = *(const bf16x8*)&B1[oB[j]];
        if (t + 2 < 16) stage(cur, 0, aS0 + k2, aS1 + k2);
        __builtin_amdgcn_s_barrier();
        asm volatile("s_waitcnt lgkmcnt(0)" ::: "memory");
        __builtin_amdgcn_s_setprio(1);
#pragma unroll
        for (int i = 0; i < 4; i++)
#pragma unroll
            for (int j = 0; j < 4; j++)
                acc[i][j] = __builtin_amdgcn_mfma_f32_16x16x32_bf16(
                    af[i], bfr[j], acc[i][j], 0, 0, 0);
        __builtin_amdgcn_s_setprio(0);
        __builtin_amdgcn_s_barrier();
        __builtin_amdgcn_sched_barrier(0);

        // ---------------- phase 3: kk=1, ihalf=1 ----------------
#pragma unroll
        for (int i = 0; i < 4; i++) af[i] = *(const bf16x8*)&A1[oA[4 + i]];
        if (t + 2 < 16) stage(cur, 2, bS0 + k2, bS1 + k2);
        if (t < 14) { asm volatile("s_waitcnt vmcnt(8)" ::: "memory"); }
        else        { asm volatile("s_waitcnt vmcnt(0)" ::: "memory"); }
        __builtin_amdgcn_s_barrier();
        asm volatile("s_waitcnt lgkmcnt(0)" ::: "memory");
        __builtin_amdgcn_s_setprio(1);
#pragma unroll
        for (int i = 0; i < 4; i++)
#pragma unroll
            for (int j = 0; j < 4; j++)
                acc[4 + i][j] = __builtin_amdgcn_mfma_f32_16x16x32_bf16(
                    af[i], bfr[j], acc[4 + i][j], 0, 0, 0);
        __builtin_amdgcn_s_setprio(0);
        __builtin_amdgcn_s_barrier();
        __builtin_amdgcn_sched_barrier(0);
    }

    // ---- epilogue: RoPE for q/k, transposed store for V ----
    const int p = nb >> 2;                       // 0=q, 1=k, 2=v (block-uniform)
    const int colbase = (nb & 3) * 256 + wn * 64;
    const int h = colbase >> 6;
    const int rb = quad * 4;
    const float* bias = (p == 0) ? bq : (p == 1) ? bk : bv;

    if (p == 2) {    // V transposed: [B,H,HS,T]
#pragma unroll
        for (int j = 0; j < 4; j++) {
            const int d = j * 16 + fr;
            const float bz = bias[colbase + d];
#pragma unroll
            for (int i = 0; i < 8; i++) {
                const int row0 = m0 + wm * 128 + i * 16 + rb;
                const int bb = row0 >> 11, tt = row0 & 2047;
                ushort4 st;
                st.x = f2bf(acc[i][j][0] + bz);
                st.y = f2bf(acc[i][j][1] + bz);
                st.z = f2bf(acc[i][j][2] + bz);
                st.w = f2bf(acc[i][j][3] + bz);
                *(ushort4*)&vb[((size_t)(bb * H_ + h) * HS_ + d) * T_ + tt] = st;
            }
        }
    } else {
        unsigned short* out = (p == 0) ? qb : kb;
        const float qsc = (p == 0) ? 0.18033688011111772f : 1.0f;  // 0.125*log2(e)
        const float bz0 = bias[colbase + fr];
        const float bz1 = bias[colbase + 16 + fr];
        const float bz2 = bias[colbase + 32 + fr];
        const float bz3 = bias[colbase + 48 + fr];
        const float nl = -0.41524101186279297f;   // -log2(10000)/32
        const float if0 = exp2f((float)fr * nl);
        const float if1 = exp2f((float)(fr + 16) * nl);
#pragma unroll
        for (int i = 0; i < 8; i++) {
#pragma unroll
            for (int pr = 0; pr < 4; pr++) {
                const int row = m0 + wm * 128 + i * 16 + rb + pr;
                const int bb = row >> 11, tt = row & 2047;
                float s0, c0, s1, c1;
                __sincosf((float)tt * if0, &s0, &c0);
                __sincosf((float)tt * if1, &s1, &c1);
                const float v0 = acc[i][0][pr] + bz0;
                const float v1 = acc[i][1][pr] + bz1;
                const float v2 = acc[i][2][pr] + bz2;
                const float v3 = acc[i][3][pr] + bz3;
                unsigned short* ob = out + ((size_t)(bb * H_ + h) * T_ + tt) * HS_ + fr;
                ob[0]  = f2bf((v0 * c0 - v2 * s0) * qsc);
                ob[16] = f2bf((v1 * c1 - v3 * s1) * qsc);
                ob[32] = f2bf((v2 * c0 + v0 * s0) * qsc);
                ob[48] = f2bf((v3 * c1 + v1 * s1) * qsc);
            }
        }
    }
}

// ---------------------------------------------------------------------------
// Kernel 3: MFMA flash attention, split-K flash-decoding. KVBLK=128:
// 128-key K/V tiles amortize the per-iteration fixed cost (sync, vote,
// rescale-check, Ps turnaround) over 2x the MFMA work. Same r3 dataflow:
// reg-prefetch at top, sync, compute, LDS-write at end, double-buffered.
// PV runs in two 64-key halves reusing the per-wave Ps buffer (DS ops of a
// wave are in-order -> write-after-read safe without barrier). Defer-max
// (T13), per-lane l partial, setprio (T5). LDS 72 KB -> 2 blocks/CU
// (= measured residency of the 64-key version). grid (32, 48), block 256.
// ---------------------------------------------------------------------------
__global__ __launch_bounds__(256) void attn_kernel(
    const unsigned short* __restrict__ qb, const unsigned short* __restrict__ kb,
    const unsigned short* __restrict__ vt, unsigned short* __restrict__ yb,
    unsigned short* __restrict__ Opart, float* __restrict__ Mpart)
{
    __shared__ unsigned short Ks[2][128 * 64];   // [key][d]
    __shared__ unsigned short Vs[2][64 * 128];   // [d][key]
    __shared__ unsigned short Ps[4][16 * 64];

    const int bh = blockIdx.x;
    const int b = bh >> 4, h = bh & 15;
    const int s = 47 - (int)blockIdx.y;          // LPT: biggest first
    int qt, ktlo, kthi, half;
    bool split;
    if (s < 16) {
        qt = s; ktlo = 0; kthi = ((qt + 2) >> 1) - 1; half = 0; split = false;
    } else {
        const int idx = s - 16;
        qt = 16 + (idx >> 1); half = idx & 1;
        const int n  = (qt + 2) >> 1;            // # 128-key tiles
        const int nf = (n + 1) >> 1;
        ktlo = half ? nf : 0;
        kthi = half ? n - 1 : nf - 1;
        split = true;
    }
    const int kdiag = ((qt + 2) >> 1) - 1;       // global diagonal tile index
    const int r0 = qt * 64;
    const int tid  = threadIdx.x;
    const int lane = tid & 63;
    const int wave = tid >> 6;
    const int l4   = lane & 15;
    const int quad = lane >> 4;

    const int qrow_g = r0 + wave * 16 + l4;

    bf16x8 qf[2];
    {
        const unsigned short* qp = qb + ((size_t)bh * T_ + qrow_g) * HS_ + quad * 8;
        qf[0] = *(const bf16x8*)(qp);
        qf[1] = *(const bf16x8*)(qp + 32);
    }

    floatx4 o[4];
#pragma unroll
    for (int g = 0; g < 4; g++) o[g] = (floatx4){0.f, 0.f, 0.f, 0.f};
    float m = -1e30f, l = 0.f;        // l is a PER-LANE partial (reduced at end)

    const int srow = tid >> 2;                   // 0..63
    const int sc16 = (tid & 3) * 16;
    const int ssw  = (srow & 7) * 8;             // (srow+64)&7 == srow&7
    const int psw  = (l4 & 7) * 8;

    const unsigned short* kp = kb + ((size_t)bh * T_ + srow) * HS_ + sc16;
    const unsigned short* vp = vt + ((size_t)(bh * 64 + srow)) * T_ + sc16;

    uint4 rk0, rk1, rk2, rk3, rv0, rv1, rv2, rv3;
    {
        const unsigned short* kpt = kp + (size_t)ktlo * (128 * HS_);
        rk0 = *(const uint4*)(kpt);
        rk1 = *(const uint4*)(kpt + 8);
        rk2 = *(const uint4*)(kpt + 64 * HS_);
        rk3 = *(const uint4*)(kpt + 64 * HS_ + 8);
        const unsigned short* vpt = vp + ktlo * 128;
        rv0 = *(const uint4*)(vpt);
        rv1 = *(const uint4*)(vpt + 8);
        rv2 = *(const uint4*)(vpt + 64);
        rv3 = *(const uint4*)(vpt + 72);
    }
    *(uint4*)&Ks[0][ srow       * 64 + ( sc16       ^ ssw)] = rk0;
    *(uint4*)&Ks[0][ srow       * 64 + ((sc16 + 8)  ^ ssw)] = rk1;
    *(uint4*)&Ks[0][(srow + 64) * 64 + ( sc16       ^ ssw)] = rk2;
    *(uint4*)&Ks[0][(srow + 64) * 64 + ((sc16 + 8)  ^ ssw)] = rk3;
    *(uint4*)&Vs[0][ srow * 128 + ( sc16       ^ ssw)] = rv0;
    *(uint4*)&Vs[0][ srow * 128 + ((sc16 + 8)  ^ ssw)] = rv1;
    *(uint4*)&Vs[0][ srow * 128 + ((sc16 + 64) ^ ssw)] = rv2;
    *(uint4*)&Vs[0][ srow * 128 + ((sc16 + 72) ^ ssw)] = rv3;

    for (int kt = ktlo; kt <= kthi; kt++) {
        const int cur = (kt - ktlo) & 1;
        if (kt < kthi) {                         // issue next-tile loads
            const unsigned short* kpn = kp + (size_t)(kt + 1) * (128 * HS_);
            rk0 = *(const uint4*)kpn;
            rk1 = *(const uint4*)(kpn + 8);
            rk2 = *(const uint4*)(kpn + 64 * HS_);
            rk3 = *(const uint4*)(kpn + 64 * HS_ + 8);
            const unsigned short* vpn = vp + (kt + 1) * 128;
            rv0 = *(const uint4*)vpn;
            rv1 = *(const uint4*)(vpn + 8);
            rv2 = *(const uint4*)(vpn + 64);
            rv3 = *(const uint4*)(vpn + 72);
        }
        __syncthreads();

        floatx4 sf[2][4];
        __builtin_amdgcn_s_setprio(1);
#pragma unroll
        for (int hh = 0; hh < 2; hh++)
#pragma unroll
        for (int mg = 0; mg < 4; mg++) {
            const int key = hh * 64 + mg * 16 + l4;
            const int ksw = (key & 7) * 8;
            const bf16x8 a0 = *(const bf16x8*)&Ks[cur][key * 64 + ( (quad * 8)       ^ ksw)];
            const bf16x8 a1 = *(const bf16x8*)&Ks[cur][key * 64 + (((quad * 8) + 32) ^ ksw)];
            floatx4 z = (floatx4){0.f, 0.f, 0.f, 0.f};
            z = __builtin_amdgcn_mfma_f32_16x16x32_bf16(a0, qf[0], z, 0, 0, 0);
            z = __builtin_amdgcn_mfma_f32_16x16x32_bf16(a1, qf[1], z, 0, 0, 0);
            sf[hh][mg] = z;
        }
        __builtin_amdgcn_s_setprio(0);

        if (kt == kdiag) {                       // causal mask (incl. dead half)
#pragma unroll
            for (int hh = 0; hh < 2; hh++)
#pragma unroll
            for (int mg = 0; mg < 4; mg++)
#pragma unroll
                for (int r = 0; r < 4; r++)
                    if (kt * 128 + hh * 64 + 16 * mg + quad * 4 + r > qrow_g)
                        sf[hh][mg][r] = -1e30f;
        }

        // per-lane tree max over 32 scores (no cross-lane in common path)
        float mxg[8];
#pragma unroll
        for (int hh = 0; hh < 2; hh++)
#pragma unroll
        for (int mg = 0; mg < 4; mg++)
            mxg[hh * 4 + mg] = fmaxf(fmaxf(sf[hh][mg][0], sf[hh][mg][1]),
                                     fmaxf(sf[hh][mg][2], sf[hh][mg][3]));
        const float m01 = fmaxf(mxg[0], mxg[1]), m23 = fmaxf(mxg[2], mxg[3]);
        const float m45 = fmaxf(mxg[4], mxg[5]), m67 = fmaxf(mxg[6], mxg[7]);
        float tm = fmaxf(fmaxf(m01, m23), fmaxf(m45, m67));

        // defer-max (T13): rescale only when some lane grew by > 8 (log2 units)
        if (!__all(tm <= m + 8.f)) {
            tm = fmaxf(tm, __shfl_xor(tm, 16));  // row-uniform max
            tm = fmaxf(tm, __shfl_xor(tm, 32));
            const float mnew  = fmaxf(m, tm);
            const float alpha = __builtin_amdgcn_exp2f(m - mnew);
            l *= alpha;
#pragma unroll
            for (int g = 0; g < 4; g++) o[g] = o[g] * alpha;
            m = mnew;
        }

        // PV in two 64-key halves, sharing the per-wave Ps buffer
#pragma unroll
        for (int hh = 0; hh < 2; hh++) {
            float pq[4][4];
            float ls = 0.f;
#pragma unroll
            for (int mg = 0; mg < 4; mg++) {
#pragma unroll
                for (int r = 0; r < 4; r++)
                    pq[mg][r] = __builtin_amdgcn_exp2f(sf[hh][mg][r] - m);
                ls += (pq[mg][0] + pq[mg][1]) + (pq[mg][2] + pq[mg][3]);
            }
            l += ls;                             // per-lane partial

#pragma unroll
            for (int mg = 0; mg < 4; mg++) {
                const int kb4 = 16 * mg + quad * 4;
                const int off = ((kb4 & ~7) ^ psw) | (kb4 & 7);
                uint2 w;
                w.x = pack2t(pq[mg][0], pq[mg][1]);
                w.y = pack2t(pq[mg][2], pq[mg][3]);
                *(uint2*)&Ps[wave][l4 * 64 + off] = w;
            }

            const bf16x8 pf0 = *(const bf16x8*)&Ps[wave][l4 * 64 + ( (quad * 8)       ^ psw)];
            const bf16x8 pf1 = *(const bf16x8*)&Ps[wave][l4 * 64 + (((quad * 8) + 32) ^ psw)];
            __builtin_amdgcn_s_setprio(1);
#pragma unroll
            for (int g = 0; g < 4; g++) {
                const int vd  = g * 16 + l4;
                const int vsw = (vd & 7) * 8;
                const bf16x8 va0 = *(const bf16x8*)&Vs[cur][vd * 128 + ((hh * 64 + quad * 8)      ^ vsw)];
                const bf16x8 va1 = *(const bf16x8*)&Vs[cur][vd * 128 + ((hh * 64 + quad * 8 + 32) ^ vsw)];
                o[g] = __builtin_amdgcn_mfma_f32_16x16x32_bf16(va0, pf0, o[g], 0, 0, 0);
                o[g] = __builtin_amdgcn_mfma_f32_16x16x32_bf16(va1, pf1, o[g], 0, 0, 0);
            }
            __builtin_amdgcn_s_setprio(0);
        }

        if (kt < kthi) {                         // stage next tile (off path)
            const int nxt = cur ^ 1;
            *(uint4*)&Ks[nxt][ srow       * 64 + ( sc16       ^ ssw)] = rk0;
            *(uint4*)&Ks[nxt][ srow       * 64 + ((sc16 + 8)  ^ ssw)] = rk1;
            *(uint4*)&Ks[nxt][(srow + 64) * 64 + ( sc16       ^ ssw)] = rk2;
            *(uint4*)&Ks[nxt][(srow + 64) * 64 + ((sc16 + 8)  ^ ssw)] = rk3;
            *(uint4*)&Vs[nxt][ srow * 128 + ( sc16       ^ ssw)] = rv0;
            *(uint4*)&Vs[nxt][ srow * 128 + ((sc16 + 8)  ^ ssw)] = rv1;
            *(uint4*)&Vs[nxt][ srow * 128 + ((sc16 + 64) ^ ssw)] = rv2;
            *(uint4*)&Vs[nxt][ srow * 128 + ((sc16 + 72) ^ ssw)] = rv3;
        }
    }

    // row-reduce the per-lane l partial once
    l += __shfl_xor(l, 16);
    l += __shfl_xor(l, 32);

    if (!split) {
        const float invl = 1.f / l;
        unsigned short* yrow = yb + ((size_t)(b * T_ + qrow_g) * H_ + h) * HS_;
#pragma unroll
        for (int g = 0; g < 4; g++) {
            ushort4 st;
            st.x = f2bf(o[g][0] * invl);
            st.y = f2bf(o[g][1] * invl);
            st.z = f2bf(o[g][2] * invl);
            st.w = f2bf(o[g][3] * invl);
            *(ushort4*)&yrow[16 * g + quad * 4] = st;
        }
    } else {
        const int u  = (bh * 16 + (qt - 16)) * 2 + half;
        const int rl = wave * 16 + l4;
        unsigned short* Op = Opart + (size_t)u * 4096 + rl * 64;
#pragma unroll
        for (int g = 0; g < 4; g++) {
            ushort4 st;
            st.x = f2bf(o[g][0]);
            st.y = f2bf(o[g][1]);
            st.z = f2bf(o[g][2]);
            st.w = f2bf(o[g][3]);
            *(ushort4*)&Op[16 * g + quad * 4] = st;
        }
        if (quad == 0) {
            float* ml = Mpart + (size_t)u * 128;
            ml[rl]      = m;
            ml[64 + rl] = l;
        }
    }
}

// ---------------------------------------------------------------------------
// Kernel 3b: merge split-K partials. grid 512, block 256.
// ---------------------------------------------------------------------------
__global__ __launch_bounds__(256) void attn_combine(
    const unsigned short* __restrict__ Opart, const float* __restrict__ Mpart,
    unsigned short* __restrict__ yb)
{
    const int u  = blockIdx.x;
    const int bh = u >> 4, qt = 16 + (u & 15);
    const int b = bh >> 4, h = bh & 15;
    const int t = threadIdx.x;
    const int r = t >> 2, c = (t & 3) * 16;

    const float* ml1 = Mpart + (size_t)(u * 2) * 128;
    const float* ml2 = ml1 + 128;
    const float m1 = ml1[r], l1 = ml1[64 + r];
    const float m2 = ml2[r], l2 = ml2[64 + r];
    const float M  = fmaxf(m1, m2);
    const float w1 = __builtin_amdgcn_exp2f(m1 - M);
    const float w2 = __builtin_amdgcn_exp2f(m2 - M);
    const float inv = 1.f / (l1 * w1 + l2 * w2);
    const float a1 = w1 * inv, a2 = w2 * inv;

    const unsigned short* O1 = Opart + (size_t)(u * 2)     * 4096 + r * 64 + c;
    const unsigned short* O2 = Opart + (size_t)(u * 2 + 1) * 4096 + r * 64 + c;
    unsigned short* yrow = yb + ((size_t)(b * T_ + qt * 64 + r) * H_ + h) * HS_ + c;

#pragma unroll
    for (int j = 0; j < 2; j++) {
        const uint4 u1 = *(const uint4*)(O1 + 8 * j);
        const uint4 u2 = *(const uint4*)(O2 + 8 * j);
        const unsigned int a[4] = {u1.x, u1.y, u1.z, u1.w};
        const unsigned int d[4] = {u2.x, u2.y, u2.z, u2.w};
        unsigned int ov[4];
#pragma unroll
        for (int q = 0; q < 4; q++) {
            const float y0 = bf2f((unsigned short)(a[q] & 0xffff)) * a1
                           + bf2f((unsigned short)(d[q] & 0xffff)) * a2;
            const float y1 = bf2f((unsigned short)(a[q] >> 16)) * a1
                           + bf2f((unsigned short)(d[q] >> 16)) * a2;
            ov[q] = pack2(y0, y1);
        }
        *(uint4*)(yrow + 8 * j) = make_uint4(ov[0], ov[1], ov[2], ov[3]);
    }
}

// ---------------------------------------------------------------------------
// Kernel 4: output projection, 8-phase port of the qkv schedule.
// 128x128 tile, BK=64, 4 waves (each 64x64), 64 KiB LDS (2buf x 4 regions x
// 8KB), counted vmcnt(8) with tail drain, chunk-XOR swizzle both-sides,
// XCD swizzle. grid 256 (= 32 mt x 8 nt), block 256.
// ---------------------------------------------------------------------------
__global__ __launch_bounds__(256, 2) void out_gemm(
    const unsigned short* __restrict__ A, const unsigned short* __restrict__ wcT,
    const float* __restrict__ bias, float* __restrict__ out)
{
    __shared__ unsigned short lds[32768];   // 64 KiB

    const int tid  = threadIdx.x;
    const int lane = tid & 63;
    const int wave = tid >> 6;

    // XCD swizzle: 256 % 8 == 0; consecutive swz share nt (B panel) per XCD
    const int bid = blockIdx.x;
    const int swz = (bid & 7) * 32 + (bid >> 3);
    const int nt  = swz >> 5;       // 0..7
    const int mt  = swz & 31;       // 0..31
    const int m0  = mt * 128;
    const int n0  = nt * 128;

    const int wm = wave >> 1, wn = wave & 1;       // 2 x 2 wave grid
    const int fr = lane & 15, quad = lane >> 4;

    // staging: gload g covers region rows [g*64, g*64+64); thread t ->
    // row g*64+(t>>2), physical chunk t&3; source chunk = phys ^ ((row>>1)&3)
    const int r_s = tid >> 2;                       // 0..63
    const int c_s = (tid & 3) ^ ((tid >> 3) & 3);
    const unsigned short* aS0 = A   + (size_t)(m0 + r_s) * 1024 + c_s * 8;
    const unsigned short* aS1 = aS0 + (size_t)64 * 1024;
    const unsigned short* bS0 = wcT + (size_t)(n0 + r_s) * 1024 + c_s * 8;
    const unsigned short* bS1 = bS0 + (size_t)64 * 1024;
    unsigned short* ldw = &lds[wave * 512];        // wave-uniform dest base

    auto stage = [&](int buf, int region, const unsigned short* s0,
                     const unsigned short* s1) {
        unsigned short* d = ldw + buf * 16384 + region * 4096;
        async16(s0, d);
        async16(s1, d + 2048);
    };

    // fragment read offsets (ushort units), swizzled
    int oA[4], oB[4];
#pragma unroll
    for (int i = 0; i < 4; i++) {
        const int r = wm * 64 + i * 16 + fr;
        oA[i] = r * 32 + ((quad ^ ((r >> 1) & 3)) << 3);
    }
#pragma unroll
    for (int j = 0; j < 4; j++) {
        const int r = wn * 64 + j * 16 + fr;
        oB[j] = r * 32 + ((quad ^ ((r >> 1) & 3)) << 3);
    }

    floatx4 acc[4][4];
#pragma unroll
    for (int i = 0; i < 4; i++)
#pragma unroll
        for (int j = 0; j < 4; j++) acc[i][j] = (floatx4){0.f, 0.f, 0.f, 0.f};

    // prologue (12 issued; vmcnt(8) -> first 4 = A_k0(0), B_k0(0) landed)
    stage(0, 0, aS0,      aS1);
    stage(0, 2, bS0,      bS1);
    stage(0, 1, aS0 + 32, aS1 + 32);
    stage(0, 3, bS0 + 32, bS1 + 32);
    stage(1, 0, aS0 + 64, aS1 + 64);
    stage(1, 2, bS0 + 64, bS1 + 64);
    asm volatile("s_waitcnt vmcnt(8)" ::: "memory");
    __builtin_amdgcn_s_barrier();
    __builtin_amdgcn_sched_barrier(0);

    bf16x8 af[2], bfr[4];
#pragma unroll 2
    for (int t = 0; t < 16; ++t) {
        const int cur = t & 1, nxt = cur ^ 1;
        const unsigned short* A0 = &lds[cur * 16384];
        const unsigned short* A1 = A0 + 4096;
        const unsigned short* B0 = A0 + 8192;
        const unsigned short* B1 = A0 + 12288;
        const int k1 = (t + 1) * 64, k2 = (t + 2) * 64;

        // ---------------- phase 0: kk=0, ihalf=0 ----------------
#pragma unroll
        for (int i = 0; i < 2; i++) af[i]  = *(const bf16x8*)&A0[oA[i]];
#pragma unroll
        for (int j = 0; j < 4; j++) bfr[j] = *(const bf16x8*)&B0[oB[j]];
        if (t + 1 < 16) stage(nxt, 1, aS0 + k1 + 32, aS1 + k1 + 32);
        __builtin_amdgcn_s_barrier();
        asm volatile("s_waitcnt lgkmcnt(0)" ::: "memory");
        __builtin_amdgcn_s_setprio(1);
#pragma unroll
        for (int i = 0; i < 2; i++)
#pragma unroll
            for (int j = 0; j < 4; j++)
                acc[i][j] = __builtin_amdgcn_mfma_f32_16x16x32_bf16(
                    af[i], bfr[j], acc[i][j], 0, 0, 0);
        __builtin_amdgcn_s_setprio(0);
        __builtin_amdgcn_s_barrier();
        __builtin_amdgcn_sched_barrier(0);

        // ---------------- phase 1: kk=0, ihalf=1 ----------------
#pragma unroll
        for (int i = 0; i < 2; i++) af[i] = *(const bf16x8*)&A0[oA[2 + i]];
        if (t + 1 < 16) stage(nxt, 3, bS0 + k1 + 32, bS1 + k1 + 32);
        if (t < 15) { asm volatile("s_waitcnt vmcnt(8)" ::: "memory"); }
        else        { asm volatile("s_waitcnt vmcnt(0)" ::: "memory"); }
        __builtin_amdgcn_s_barrier();
        asm volatile("s_waitcnt lgkmcnt(0)" ::: "memory");
        __builtin_amdgcn_s_setprio(1);
#pragma unroll
        for (int i = 0; i < 2; i++)
#pragma unroll
            for (int j = 0; j < 4; j++)
                acc[2 + i][j] = __builtin_amdgcn_mfma_f32_16x16x32_bf16(
                    af[i], bfr[j], acc[2 + i][j], 0, 0, 0);
        __builtin_amdgcn_s_setprio(0);
        __builtin_amdgcn_s_barrier();
        __builtin_amdgcn_sched_barrier(0);

        // ---------------- phase 2: kk=1, ihalf=0 ----------------
#pragma unroll
        for (int i = 0; i < 2; i++) af[i]  = *(const bf16x8*)&A1[oA[i]];
#pragma unroll
        for (int j = 0; j < 4; j++) bfr[j] = *(const bf16x8*)&B1[oB[j]];
        if (t + 2 < 16) stage(cur, 0, aS0 + k2, aS1 + k2);
        __builtin_amdgcn_s_barrier();
        asm volatile("s_waitcnt lgkmcnt(0)" ::: "memory");
        __builtin_amdgcn_s_setprio(1);
#pragma unroll
        for (int i = 0; i < 2; i++)
#pragma unroll
            for (int j = 0; j < 4; j++)
                acc[i][j] = __builtin_amdgcn_mfma_f32_16x16x32_bf16(
                    af[i], bfr[j], acc[i][j], 0, 0, 0);
        __builtin_amdgcn_s_setprio(0);
        __builtin_amdgcn_s_barrier();
        __builtin_amdgcn_sched_barrier(0);

        // ---------------- phase 3: kk=1, ihalf=1 ----------------
#pragma unroll
        for (int i = 0; i < 2; i++) af[i] = *(const bf16x8*)&A1[oA[2 + i]];
        if (t + 2 < 16) stage(cur, 2, bS0 + k2, bS1 + k2);
        if (t < 14) { asm volatile("s_waitcnt vmcnt(8)" ::: "memory"); }
        else        { asm volatile("s_waitcnt vmcnt(0)" ::: "memory"); }
        __builtin_amdgcn_s_barrier();
        asm volatile("s_waitcnt lgkmcnt(0)" ::: "memory");
        __builtin_amdgcn_s_setprio(1);
#pragma unroll
        for (int i = 0; i < 2; i++)
#pragma unroll
            for (int j = 0; j < 4; j++)
                acc[2 + i][j] = __builtin_amdgcn_mfma_f32_16x16x32_bf16(
                    af[i], bfr[j], acc[2 + i][j], 0, 0, 0);
        __builtin_amdgcn_s_setprio(0);
        __builtin_amdgcn_s_barrier();
        __builtin_amdgcn_sched_barrier(0);
    }

    // epilogue: fp32 store + bias
    const int rbase = quad * 4;
#pragma unroll
    for (int j = 0; j < 4; j++) {
        const int col = n0 + wn * 64 + j * 16 + fr;
        const float bz = bias[col];
#pragma unroll
        for (int i = 0; i < 4; i++) {
#pragma unroll
            for (int pr = 0; pr < 4; pr++) {
                const int row = m0 + wm * 64 + i * 16 + rbase + pr;
                out[(size_t)row * N_ + col] = acc[i][j][pr] + bz;
            }
        }
    }
}

// ---------------------------------------------------------------------------
extern "C" void kernel_launch(void* const* d_in, const int* in_sizes, int n_in,
                              void* d_out, int out_size, void* d_ws, size_t ws_size,
                              hipStream_t stream) {
    const float* x  = (const float*)d_in[0];
    const float* wq = (const float*)d_in[1];
    const float* bq = (const float*)d_in[2];
    const float* wk = (const float*)d_in[3];
    const float* bk = (const float*)d_in[4];
    const float* wv = (const float*)d_in[5];
    const float* bv = (const float*)d_in[6];
    const float* wc = (const float*)d_in[7];
    const float* bc = (const float*)d_in[8];
    float* out = (float*)d_out;

    // ws (ushort units): qb 0, kb 4M, vb 8M, yb 12M, xb 16M, wT 20M..24M (48 MB)
    unsigned short* ws  = (unsigned short*)d_ws;
    unsigned short* qb  = ws;                        // [B,H,T,HS] rope+scale
    unsigned short* kb  = ws + (size_t)4194304;      // [B,H,T,HS] rope
    unsigned short* vb  = ws + (size_t)8388608;      // [B,H,HS,T] (V^T)
    unsigned short* yb  = ws + (size_t)12582912;     // [B,T,C]
    unsigned short* xb  = ws + (size_t)16777216;     // x bf16 (dead after qkv)
    unsigned short* wT  = ws + (size_t)20971520;     // 4x bf16 [n][k]
    unsigned short* wcT = wT + ((size_t)3 << 20);
    unsigned short* Opart = xb;                      // split-K O' partials
    float*          Mpart = (float*)wT;              // split-K m,l partials

    prep_kernel<<<5120, 256, 0, stream>>>(x, wq, wk, wv, wc, xb, wT);
    qkv_gemm<<<192, 512, 0, stream>>>(xb, wT, bq, bk, bv, qb, kb, vb);
    attn_kernel<<<dim3(32, 48), 256, 0, stream>>>(qb, kb, vb, yb, Opart, Mpart);
    attn_combine<<<512, 256, 0, stream>>>(Opart, Mpart, yb);
    out_gemm<<<256, 256, 0, stream>>>(yb, wcT, bc, out);
}

// Round 9
// 187.912 us; speedup vs baseline: 1.0166x; 1.0166x over previous
//
#include <hip/hip_runtime.h>

#define B_  2
#define T_  2048
#define C_  1024
#define H_  16
#define HS_ 64
#define M_  4096
#define N_  1024
#define K_  1024

typedef float floatx4 __attribute__((ext_vector_type(4)));
typedef short bf16x8  __attribute__((ext_vector_type(8)));

__device__ __forceinline__ float bf2f(unsigned short u) {
    return __uint_as_float(((unsigned int)u) << 16);
}
__device__ __forceinline__ unsigned short f2bf(float f) {
    unsigned int u = __float_as_uint(f);
    return (unsigned short)((u + 0x7fffu + ((u >> 16) & 1u)) >> 16);
}
__device__ __forceinline__ unsigned int pack2(float a, float b) {
    return (unsigned int)f2bf(a) | ((unsigned int)f2bf(b) << 16);
}
// truncating bf16 pair pack: one v_perm_b32
__device__ __forceinline__ unsigned int pack2t(float a, float b) {
    return __builtin_amdgcn_perm(__float_as_uint(b), __float_as_uint(a), 0x07060302u);
}
// async global->LDS, 16B per lane; lds dest = wave-uniform base + lane*16
__device__ __forceinline__ void async16(const unsigned short* g, unsigned short* l) {
    __builtin_amdgcn_global_load_lds(
        (const __attribute__((address_space(1))) unsigned int*)g,
        (__attribute__((address_space(3))) unsigned int*)l, 16, 0, 0);
}

// ---------------------------------------------------------------------------
// Prep (merged): blocks 0..4095 convert x fp32->bf16; blocks 4096..5119
// transpose+convert weights; blocks 5120..5183 build the RoPE float2 table
// tab[t][f] = (cos, sin)(t * 10000^(-f/32)), t<2048, f<32 (512 KB, lives in
// the yb region which is dead until attn writes it).
// grid 5184, block 256.
// ---------------------------------------------------------------------------
__global__ __launch_bounds__(256) void prep_kernel(
    const float* __restrict__ x,
    const float* __restrict__ w0, const float* __restrict__ w1,
    const float* __restrict__ w2, const float* __restrict__ w3,
    unsigned short* __restrict__ xb, unsigned short* __restrict__ wTall,
    float2* __restrict__ tab)
{
    __shared__ float tile[64][65];
    const int bid = blockIdx.x;
    const int t = threadIdx.x;
    if (bid < 4096) {
        const size_t i = ((size_t)bid * 256 + t) * 4;
        const float4 v = *(const float4*)(x + i);
        ushort4 st;
        st.x = f2bf(v.x); st.y = f2bf(v.y); st.z = f2bf(v.z); st.w = f2bf(v.w);
        *(ushort4*)(xb + i) = st;
        return;
    }
    if (bid >= 5120) {                     // RoPE table: 64 blocks x 1024 entries
        const float nl = -0.41524101186279297f;   // -log2(10000)/32
        const int base = (bid - 5120) * 1024 + t * 4;
#pragma unroll
        for (int j = 0; j < 4; j++) {
            const int idx = base + j;
            const int tt = idx >> 5, f = idx & 31;
            float s, c;
            __sincosf((float)tt * exp2f((float)f * nl), &s, &c);
            tab[idx] = make_float2(c, s);
        }
        return;
    }
    const int zb = bid - 4096;
    const int z = zb >> 8, rem = zb & 255;
    const float* w = (z == 0) ? w0 : (z == 1) ? w1 : (z == 2) ? w2 : w3;
    unsigned short* wT = wTall + ((size_t)z << 20);
    const int n0 = (rem & 15) * 64, k0 = (rem >> 4) * 64;

    const int r = t >> 2, cq = (t & 3) * 16;
    const float4* src = (const float4*)(w + (size_t)(k0 + r) * N_ + n0 + cq);
    const float4 v0 = src[0], v1 = src[1], v2 = src[2], v3 = src[3];
    tile[r][cq+0]=v0.x; tile[r][cq+1]=v0.y; tile[r][cq+2]=v0.z; tile[r][cq+3]=v0.w;
    tile[r][cq+4]=v1.x; tile[r][cq+5]=v1.y; tile[r][cq+6]=v1.z; tile[r][cq+7]=v1.w;
    tile[r][cq+8]=v2.x; tile[r][cq+9]=v2.y; tile[r][cq+10]=v2.z; tile[r][cq+11]=v2.w;
    tile[r][cq+12]=v3.x; tile[r][cq+13]=v3.y; tile[r][cq+14]=v3.z; tile[r][cq+15]=v3.w;
    __syncthreads();

    const int rn = t >> 2, ck = (t & 3) * 16;
    unsigned int o[8];
#pragma unroll
    for (int ii = 0; ii < 8; ii++)
        o[ii] = pack2(tile[ck + 2*ii][rn], tile[ck + 2*ii + 1][rn]);
    unsigned short* dst = wT + (size_t)(n0 + rn) * K_ + k0 + ck;
    *(uint4*)dst       = make_uint4(o[0], o[1], o[2], o[3]);
    *(uint4*)(dst + 8) = make_uint4(o[4], o[5], o[6], o[7]);
}

// ---------------------------------------------------------------------------
// Kernel 1: fused QKV GEMM + RoPE epilogue.
// Single GEMM M=4096, N=3072, 256x256 tile, BK=64, 8 waves, 8-phase schedule
// with counted vmcnt (T3+T4), LDS chunk-XOR swizzle (T2), setprio (T5).
// Tail drain: vmcnt(0) when stages are predicated off (t>=14/15).
// RoPE epilogue reads the precomputed cos/sin table (no per-element sincos).
// grid 192, block 512.
// ---------------------------------------------------------------------------
__global__ __launch_bounds__(512, 2) void qkv_gemm(
    const unsigned short* __restrict__ xb, const unsigned short* __restrict__ wT,
    const float* __restrict__ bq, const float* __restrict__ bk,
    const float* __restrict__ bv, const float2* __restrict__ tab,
    unsigned short* __restrict__ qb, unsigned short* __restrict__ kb,
    unsigned short* __restrict__ vb)
{
    __shared__ unsigned short lds[65536];   // 128 KiB

    const int tid  = threadIdx.x;
    const int lane = tid & 63;
    const int wave = tid >> 6;

    // XCD-aware swizzle (192 % 8 == 0 -> simple bijective form)
    const int bid = blockIdx.x;
    const int swz = (bid & 7) * 24 + (bid >> 3);
    const int nb  = swz % 12;
    const int mb  = swz / 12;
    const int m0  = mb * 256;
    const int n0g = nb * 256;

    const int wm = wave >> 2, wn = wave & 3;       // 2 x 4 wave grid
    const int fr = lane & 15, quad = lane >> 4;

    // staging: gload g covers LDS rows [g*128, g*128+128); thread t ->
    // row g*128+(t>>2), physical chunk t&3; source chunk = phys ^ ((row>>1)&3)
    const int r_s = tid >> 2;
    const int c_s = (tid & 3) ^ ((tid >> 3) & 3);
    const unsigned short* aS0 = xb + (size_t)(m0 + r_s) * 1024 + c_s * 8;
    const unsigned short* aS1 = aS0 + (size_t)128 * 1024;
    const unsigned short* bS0 = wT + (size_t)(n0g + r_s) * 1024 + c_s * 8;
    const unsigned short* bS1 = bS0 + (size_t)128 * 1024;
    unsigned short* ldw = &lds[wave * 512];        // wave-uniform dest base

    auto stage = [&](int buf, int region, const unsigned short* s0,
                     const unsigned short* s1) {
        unsigned short* d = ldw + buf * 32768 + region * 8192;
        async16(s0, d);
        async16(s1, d + 4096);
    };

    // fragment read offsets (ushort units), swizzled
    int oA[8], oB[4];
#pragma unroll
    for (int i = 0; i < 8; i++) {
        const int r = wm * 128 + i * 16 + fr;
        oA[i] = r * 32 + ((quad ^ ((r >> 1) & 3)) << 3);
    }
#pragma unroll
    for (int j = 0; j < 4; j++) {
        const int r = wn * 64 + j * 16 + fr;
        oB[j] = r * 32 + ((quad ^ ((r >> 1) & 3)) << 3);
    }

    floatx4 acc[8][4];
#pragma unroll
    for (int i = 0; i < 8; i++)
#pragma unroll
        for (int j = 0; j < 4; j++) acc[i][j] = (floatx4){0.f, 0.f, 0.f, 0.f};

    // prologue
    stage(0, 0, aS0,      aS1);
    stage(0, 2, bS0,      bS1);
    stage(0, 1, aS0 + 32, aS1 + 32);
    stage(0, 3, bS0 + 32, bS1 + 32);
    stage(1, 0, aS0 + 64, aS1 + 64);
    stage(1, 2, bS0 + 64, bS1 + 64);
    asm volatile("s_waitcnt vmcnt(8)" ::: "memory");   // k0(0) landed
    __builtin_amdgcn_s_barrier();
    __builtin_amdgcn_sched_barrier(0);

    bf16x8 af[4], bfr[4];
#pragma unroll 2
    for (int t = 0; t < 16; ++t) {
        const int cur = t & 1, nxt = cur ^ 1;
        const unsigned short* A0 = &lds[cur * 32768];
        const unsigned short* A1 = A0 + 8192;
        const unsigned short* B0 = A0 + 16384;
        const unsigned short* B1 = A0 + 24576;
        const int k1 = (t + 1) * 64, k2 = (t + 2) * 64;

        // ---------------- phase 0: kk=0, ihalf=0 ----------------
#pragma unroll
        for (int i = 0; i < 4; i++) af[i]  = *(const bf16x8*)&A0[oA[i]];
#pragma unroll
        for (int j = 0; j < 4; j++) bfr[j] = *(const bf16x8*)&B0[oB[j]];
        if (t + 1 < 16) stage(nxt, 1, aS0 + k1 + 32, aS1 + k1 + 32);
        __builtin_amdgcn_s_barrier();
        asm volatile("s_waitcnt lgkmcnt(0)" ::: "memory");
        __builtin_amdgcn_s_setprio(1);
#pragma unroll
        for (int i = 0; i < 4; i++)
#pragma unroll
            for (int j = 0; j < 4; j++)
                acc[i][j] = __builtin_amdgcn_mfma_f32_16x16x32_bf16(
                    af[i], bfr[j], acc[i][j], 0, 0, 0);
        __builtin_amdgcn_s_setprio(0);
        __builtin_amdgcn_s_barrier();
        __builtin_amdgcn_sched_barrier(0);

        // ---------------- phase 1: kk=0, ihalf=1 ----------------
#pragma unroll
        for (int i = 0; i < 4; i++) af[i] = *(const bf16x8*)&A0[oA[4 + i]];
        if (t + 1 < 16) stage(nxt, 3, bS0 + k1 + 32, bS1 + k1 + 32);
        if (t < 15) { asm volatile("s_waitcnt vmcnt(8)" ::: "memory"); }
        else        { asm volatile("s_waitcnt vmcnt(0)" ::: "memory"); }
        __builtin_amdgcn_s_barrier();
        asm volatile("s_waitcnt lgkmcnt(0)" ::: "memory");
        __builtin_amdgcn_s_setprio(1);
#pragma unroll
        for (int i = 0; i < 4; i++)
#pragma unroll
            for (int j = 0; j < 4; j++)
                acc[4 + i][j] = __builtin_amdgcn_mfma_f32_16x16x32_bf16(
                    af[i], bfr[j], acc[4 + i][j], 0, 0, 0);
        __builtin_amdgcn_s_setprio(0);
        __builtin_amdgcn_s_barrier();
        __builtin_amdgcn_sched_barrier(0);

        // ---------------- phase 2: kk=1, ihalf=0 ----------------
#pragma unroll
        for (int i = 0; i < 4; i++) af[i]  = *(const bf16x8*)&A1[oA[i]];
#pragma unroll
        for (int j = 0; j < 4; j++) bfr[j] = *(const bf16x8*)&B1[oB[j]];
        if (t + 2 < 16) stage(cur, 0, aS0 + k2, aS1 + k2);
        __builtin_amdgcn_s_barrier();
        asm volatile("s_waitcnt lgkmcnt(0)" ::: "memory");
        __builtin_amdgcn_s_setprio(1);
#pragma unroll
        for (int i = 0; i < 4; i++)
#pragma unroll
            for (int j = 0; j < 4; j++)
                acc[i][j] = __builtin_amdgcn_mfma_f32_16x16x32_bf16(
                    af[i], bfr[j], acc[i][j], 0, 0, 0);
        __builtin_amdgcn_s_setprio(0);
        __builtin_amdgcn_s_barrier();
        __builtin_amdgcn_sched_barrier(0);

        // ---------------- phase 3: kk=1, ihalf=1 ----------------
#pragma unroll
        for (int i = 0; i < 4; i++) af[i] = *(const bf16x8*)&A1[oA[4 + i]];
        if (t + 2 < 16) stage(cur, 2, bS0 + k2, bS1 + k2);
        if (t < 14) { asm volatile("s_waitcnt vmcnt(8)" ::: "memory"); }
        else        { asm volatile("s_waitcnt vmcnt(0)" ::: "memory"); }
        __builtin_amdgcn_s_barrier();
        asm volatile("s_waitcnt lgkmcnt(0)" ::: "memory");
        __builtin_amdgcn_s_setprio(1);
#pragma unroll
        for (int i = 0; i < 4; i++)
#pragma unroll
            for (int j = 0; j < 4; j++)
                acc[4 + i][j] = __builtin_amdgcn_mfma_f32_16x16x32_bf16(
                    af[i], bfr[j], acc[4 + i][j], 0, 0, 0);
        __builtin_amdgcn_s_setprio(0);
        __builtin_amdgcn_s_barrier();
        __builtin_amdgcn_sched_barrier(0);
    }

    // ---- epilogue: RoPE for q/k (table-driven), transposed store for V ----
    const int p = nb >> 2;                       // 0=q, 1=k, 2=v (block-uniform)
    const int colbase = (nb & 3) * 256 + wn * 64;
    const int h = colbase >> 6;
    const int rb = quad * 4;
    const float* bias = (p == 0) ? bq : (p == 1) ? bk : bv;

    if (p == 2) {    // V transposed: [B,H,HS,T]
#pragma unroll
        for (int j = 0; j < 4; j++) {
            const int d = j * 16 + fr;
            const float bz = bias[colbase + d];
#pragma unroll
            for (int i = 0; i < 8; i++) {
                const int row0 = m0 + wm * 128 + i * 16 + rb;
                const int bb = row0 >> 11, tt = row0 & 2047;
                ushort4 st;
                st.x = f2bf(acc[i][j][0] + bz);
                st.y = f2bf(acc[i][j][1] + bz);
                st.z = f2bf(acc[i][j][2] + bz);
                st.w = f2bf(acc[i][j][3] + bz);
                *(ushort4*)&vb[((size_t)(bb * H_ + h) * HS_ + d) * T_ + tt] = st;
            }
        }
    } else {
        unsigned short* out = (p == 0) ? qb : kb;
        const float qsc = (p == 0) ? 0.18033688011111772f : 1.0f;  // 0.125*log2(e)
        const float bz0 = bias[colbase + fr];
        const float bz1 = bias[colbase + 16 + fr];
        const float bz2 = bias[colbase + 32 + fr];
        const float bz3 = bias[colbase + 48 + fr];
#pragma unroll
        for (int i = 0; i < 8; i++) {
#pragma unroll
            for (int pr = 0; pr < 4; pr++) {
                const int row = m0 + wm * 128 + i * 16 + rb + pr;
                const int bb = row >> 11, tt = row & 2047;
                const float2 cs0 = tab[tt * 32 + fr];
                const float2 cs1 = tab[tt * 32 + fr + 16];
                const float c0 = cs0.x, s0 = cs0.y;
                const float c1 = cs1.x, s1 = cs1.y;
                const float v0 = acc[i][0][pr] + bz0;
                const float v1 = acc[i][1][pr] + bz1;
                const float v2 = acc[i][2][pr] + bz2;
                const float v3 = acc[i][3][pr] + bz3;
                unsigned short* ob = out + ((size_t)(bb * H_ + h) * T_ + tt) * HS_ + fr;
                ob[0]  = f2bf((v0 * c0 - v2 * s0) * qsc);
                ob[16] = f2bf((v1 * c1 - v3 * s1) * qsc);
                ob[32] = f2bf((v2 * c0 + v0 * s0) * qsc);
                ob[48] = f2bf((v3 * c1 + v1 * s1) * qsc);
            }
        }
    }
}

// ---------------------------------------------------------------------------
// Kernel 3: MFMA flash attention, split-K flash-decoding.
// Double-buffered K/V (prefetch regs at top, LDS write at iter end, off the
// critical path). Defer-max (T13) with shfl ONLY in rescale branch; per-lane
// l partial (cross-lane l-reduce once at end); setprio (T5); tree reductions.
// grid (32, 48), block 256.  [r6 version — best measured: 48.1 us]
// ---------------------------------------------------------------------------
__global__ __launch_bounds__(256) void attn_kernel(
    const unsigned short* __restrict__ qb, const unsigned short* __restrict__ kb,
    const unsigned short* __restrict__ vt, unsigned short* __restrict__ yb,
    unsigned short* __restrict__ Opart, float* __restrict__ Mpart)
{
    __shared__ unsigned short Ks[2][64 * 64];
    __shared__ unsigned short Vs[2][64 * 64];
    __shared__ unsigned short Ps[4][16 * 64];

    const int bh = blockIdx.x;
    const int b = bh >> 4, h = bh & 15;
    const int s = 47 - (int)blockIdx.y;          // LPT: biggest first
    int qt, ktlo, kthi, half;
    bool split;
    if (s < 16) { qt = s; ktlo = 0; kthi = qt; half = 0; split = false; }
    else {
        const int idx = s - 16;
        qt = 16 + (idx >> 1); half = idx & 1;
        const int nf = (qt + 2) >> 1;
        ktlo = half ? nf : 0;
        kthi = half ? qt : nf - 1;
        split = true;
    }
    const int r0 = qt * 64;
    const int tid  = threadIdx.x;
    const int lane = tid & 63;
    const int wave = tid >> 6;
    const int l4   = lane & 15;
    const int quad = lane >> 4;

    const int qrow_g = r0 + wave * 16 + l4;

    bf16x8 qf[2];
    {
        const unsigned short* qp = qb + ((size_t)bh * T_ + qrow_g) * HS_ + quad * 8;
        qf[0] = *(const bf16x8*)(qp);
        qf[1] = *(const bf16x8*)(qp + 32);
    }

    floatx4 o[4];
#pragma unroll
    for (int g = 0; g < 4; g++) o[g] = (floatx4){0.f, 0.f, 0.f, 0.f};
    float m = -1e30f, l = 0.f;        // l is a PER-LANE partial (reduced at end)

    const int srow = tid >> 2;
    const int sc16 = (tid & 3) * 16;
    const int ssw  = (srow & 7) * 8;
    const int psw  = (l4 & 7) * 8;

    const unsigned short* kp = kb + ((size_t)bh * T_ + srow) * HS_ + sc16;
    const unsigned short* vp = vt + ((size_t)(bh * 64 + srow)) * T_ + sc16;

    uint4 rk0 = *(const uint4*)(kp + (size_t)ktlo * 64 * HS_);
    uint4 rk1 = *(const uint4*)(kp + (size_t)ktlo * 64 * HS_ + 8);
    uint4 rv0 = *(const uint4*)(vp + ktlo * 64);
    uint4 rv1 = *(const uint4*)(vp + ktlo * 64 + 8);
    *(uint4*)&Ks[0][srow * 64 + ( sc16      ^ ssw)] = rk0;
    *(uint4*)&Ks[0][srow * 64 + ((sc16 + 8) ^ ssw)] = rk1;
    *(uint4*)&Vs[0][srow * 64 + ( sc16      ^ ssw)] = rv0;
    *(uint4*)&Vs[0][srow * 64 + ((sc16 + 8) ^ ssw)] = rv1;

    for (int kt = ktlo; kt <= kthi; kt++) {
        const int cur = (kt - ktlo) & 1;
        if (kt < kthi) {                               // issue next-tile loads
            const unsigned short* kpn = kp + (size_t)(kt + 1) * (64 * HS_);
            const unsigned short* vpn = vp + (kt + 1) * 64;
            rk0 = *(const uint4*)kpn;
            rk1 = *(const uint4*)(kpn + 8);
            rv0 = *(const uint4*)vpn;
            rv1 = *(const uint4*)(vpn + 8);
        }
        __syncthreads();

        floatx4 sf[4];
        __builtin_amdgcn_s_setprio(1);
#pragma unroll
        for (int mg = 0; mg < 4; mg++) {
            const int key = mg * 16 + l4;
            const int ksw = (key & 7) * 8;
            const bf16x8 a0 = *(const bf16x8*)&Ks[cur][key * 64 + ( (quad * 8)       ^ ksw)];
            const bf16x8 a1 = *(const bf16x8*)&Ks[cur][key * 64 + (((quad * 8) + 32) ^ ksw)];
            floatx4 z = (floatx4){0.f, 0.f, 0.f, 0.f};
            z = __builtin_amdgcn_mfma_f32_16x16x32_bf16(a0, qf[0], z, 0, 0, 0);
            z = __builtin_amdgcn_mfma_f32_16x16x32_bf16(a1, qf[1], z, 0, 0, 0);
            sf[mg] = z;
        }
        __builtin_amdgcn_s_setprio(0);

        if (kt == qt) {
#pragma unroll
            for (int mg = 0; mg < 4; mg++)
#pragma unroll
                for (int r = 0; r < 4; r++)
                    if (kt * 64 + 16 * mg + quad * 4 + r > qrow_g)
                        sf[mg][r] = -1e30f;
        }

        // per-lane tree max (no cross-lane in common path)
        float mx[4];
#pragma unroll
        for (int mg = 0; mg < 4; mg++)
            mx[mg] = fmaxf(fmaxf(sf[mg][0], sf[mg][1]),
                           fmaxf(sf[mg][2], sf[mg][3]));
        float tm = fmaxf(fmaxf(mx[0], mx[1]), fmaxf(mx[2], mx[3]));

        // defer-max (T13): rescale only when some lane grew by > 8 (log2 units)
        if (!__all(tm <= m + 8.f)) {
            tm = fmaxf(tm, __shfl_xor(tm, 16));        // row-uniform max
            tm = fmaxf(tm, __shfl_xor(tm, 32));
            const float mnew  = fmaxf(m, tm);
            const float alpha = __builtin_amdgcn_exp2f(m - mnew);
            l *= alpha;
#pragma unroll
            for (int g = 0; g < 4; g++) o[g] = o[g] * alpha;
            m = mnew;
        }

        float p[4][4];
        float psg[4];
#pragma unroll
        for (int mg = 0; mg < 4; mg++) {
#pragma unroll
            for (int r = 0; r < 4; r++)
                p[mg][r] = __builtin_amdgcn_exp2f(sf[mg][r] - m);
            psg[mg] = (p[mg][0] + p[mg][1]) + (p[mg][2] + p[mg][3]);
        }
        l += (psg[0] + psg[1]) + (psg[2] + psg[3]);    // per-lane partial

#pragma unroll
        for (int mg = 0; mg < 4; mg++) {
            const int kb4 = 16 * mg + quad * 4;
            const int off = ((kb4 & ~7) ^ psw) | (kb4 & 7);
            uint2 w;
            w.x = pack2t(p[mg][0], p[mg][1]);
            w.y = pack2t(p[mg][2], p[mg][3]);
            *(uint2*)&Ps[wave][l4 * 64 + off] = w;
        }

        const bf16x8 pf0 = *(const bf16x8*)&Ps[wave][l4 * 64 + ( (quad * 8)       ^ psw)];
        const bf16x8 pf1 = *(const bf16x8*)&Ps[wave][l4 * 64 + (((quad * 8) + 32) ^ psw)];
        __builtin_amdgcn_s_setprio(1);
#pragma unroll
        for (int g = 0; g < 4; g++) {
            const int vd  = g * 16 + l4;
            const int vsw = (vd & 7) * 8;
            const bf16x8 va0 = *(const bf16x8*)&Vs[cur][vd * 64 + ( (quad * 8)       ^ vsw)];
            const bf16x8 va1 = *(const bf16x8*)&Vs[cur][vd * 64 + (((quad * 8) + 32) ^ vsw)];
            o[g] = __builtin_amdgcn_mfma_f32_16x16x32_bf16(va0, pf0, o[g], 0, 0, 0);
            o[g] = __builtin_amdgcn_mfma_f32_16x16x32_bf16(va1, pf1, o[g], 0, 0, 0);
        }
        __builtin_amdgcn_s_setprio(0);

        if (kt < kthi) {                               // stage next tile (off path)
            const int nxt = cur ^ 1;
            *(uint4*)&Ks[nxt][srow * 64 + ( sc16      ^ ssw)] = rk0;
            *(uint4*)&Ks[nxt][srow * 64 + ((sc16 + 8) ^ ssw)] = rk1;
            *(uint4*)&Vs[nxt][srow * 64 + ( sc16      ^ ssw)] = rv0;
            *(uint4*)&Vs[nxt][srow * 64 + ((sc16 + 8) ^ ssw)] = rv1;
        }
    }

    // row-reduce the per-lane l partial once
    l += __shfl_xor(l, 16);
    l += __shfl_xor(l, 32);

    if (!split) {
        const float invl = 1.f / l;
        unsigned short* yrow = yb + ((size_t)(b * T_ + qrow_g) * H_ + h) * HS_;
#pragma unroll
        for (int g = 0; g < 4; g++) {
            ushort4 st;
            st.x = f2bf(o[g][0] * invl);
            st.y = f2bf(o[g][1] * invl);
            st.z = f2bf(o[g][2] * invl);
            st.w = f2bf(o[g][3] * invl);
            *(ushort4*)&yrow[16 * g + quad * 4] = st;
        }
    } else {
        const int u  = (bh * 16 + (qt - 16)) * 2 + half;
        const int rl = wave * 16 + l4;
        unsigned short* Op = Opart + (size_t)u * 4096 + rl * 64;
#pragma unroll
        for (int g = 0; g < 4; g++) {
            ushort4 st;
            st.x = f2bf(o[g][0]);
            st.y = f2bf(o[g][1]);
            st.z = f2bf(o[g][2]);
            st.w = f2bf(o[g][3]);
            *(ushort4*)&Op[16 * g + quad * 4] = st;
        }
        if (quad == 0) {
            float* ml = Mpart + (size_t)u * 128;
            ml[rl]      = m;
            ml[64 + rl] = l;
        }
    }
}

// ---------------------------------------------------------------------------
// Kernel 3b: merge split-K partials. grid 512, block 256.
// ---------------------------------------------------------------------------
__global__ __launch_bounds__(256) void attn_combine(
    const unsigned short* __restrict__ Opart, const float* __restrict__ Mpart,
    unsigned short* __restrict__ yb)
{
    const int u  = blockIdx.x;
    const int bh = u >> 4, qt = 16 + (u & 15);
    const int b = bh >> 4, h = bh & 15;
    const int t = threadIdx.x;
    const int r = t >> 2, c = (t & 3) * 16;

    const float* ml1 = Mpart + (size_t)(u * 2) * 128;
    const float* ml2 = ml1 + 128;
    const float m1 = ml1[r], l1 = ml1[64 + r];
    const float m2 = ml2[r], l2 = ml2[64 + r];
    const float M  = fmaxf(m1, m2);
    const float w1 = __builtin_amdgcn_exp2f(m1 - M);
    const float w2 = __builtin_amdgcn_exp2f(m2 - M);
    const float inv = 1.f / (l1 * w1 + l2 * w2);
    const float a1 = w1 * inv, a2 = w2 * inv;

    const unsigned short* O1 = Opart + (size_t)(u * 2)     * 4096 + r * 64 + c;
    const unsigned short* O2 = Opart + (size_t)(u * 2 + 1) * 4096 + r * 64 + c;
    unsigned short* yrow = yb + ((size_t)(b * T_ + qt * 64 + r) * H_ + h) * HS_ + c;

#pragma unroll
    for (int j = 0; j < 2; j++) {
        const uint4 u1 = *(const uint4*)(O1 + 8 * j);
        const uint4 u2 = *(const uint4*)(O2 + 8 * j);
        const unsigned int a[4] = {u1.x, u1.y, u1.z, u1.w};
        const unsigned int d[4] = {u2.x, u2.y, u2.z, u2.w};
        unsigned int ov[4];
#pragma unroll
        for (int q = 0; q < 4; q++) {
            const float y0 = bf2f((unsigned short)(a[q] & 0xffff)) * a1
                           + bf2f((unsigned short)(d[q] & 0xffff)) * a2;
            const float y1 = bf2f((unsigned short)(a[q] >> 16)) * a1
                           + bf2f((unsigned short)(d[q] >> 16)) * a2;
            ov[q] = pack2(y0, y1);
        }
        *(uint4*)(yrow + 8 * j) = make_uint4(ov[0], ov[1], ov[2], ov[3]);
    }
}

// ---------------------------------------------------------------------------
// Kernel 4: output projection, 8-phase port of the qkv schedule.
// 128x128 tile, BK=64, 4 waves (each 64x64), 64 KiB LDS (2buf x 4 regions x
// 8KB), counted vmcnt(8) with tail drain, chunk-XOR swizzle both-sides,
// XCD swizzle. grid 256 (= 32 mt x 8 nt), block 256.
// ---------------------------------------------------------------------------
__global__ __launch_bounds__(256, 2) void out_gemm(
    const unsigned short* __restrict__ A, const unsigned short* __restrict__ wcT,
    const float* __restrict__ bias, float* __restrict__ out)
{
    __shared__ unsigned short lds[32768];   // 64 KiB

    const int tid  = threadIdx.x;
    const int lane = tid & 63;
    const int wave = tid >> 6;

    // XCD swizzle: 256 % 8 == 0; consecutive swz share nt (B panel) per XCD
    const int bid = blockIdx.x;
    const int swz = (bid & 7) * 32 + (bid >> 3);
    const int nt  = swz >> 5;       // 0..7
    const int mt  = swz & 31;       // 0..31
    const int m0  = mt * 128;
    const int n0  = nt * 128;

    const int wm = wave >> 1, wn = wave & 1;       // 2 x 2 wave grid
    const int fr = lane & 15, quad = lane >> 4;

    // staging: gload g covers region rows [g*64, g*64+64); thread t ->
    // row g*64+(t>>2), physical chunk t&3; source chunk = phys ^ ((row>>1)&3)
    const int r_s = tid >> 2;                       // 0..63
    const int c_s = (tid & 3) ^ ((tid >> 3) & 3);
    const unsigned short* aS0 = A   + (size_t)(m0 + r_s) * 1024 + c_s * 8;
    const unsigned short* aS1 = aS0 + (size_t)64 * 1024;
    const unsigned short* bS0 = wcT + (size_t)(n0 + r_s) * 1024 + c_s * 8;
    const unsigned short* bS1 = bS0 + (size_t)64 * 1024;
    unsigned short* ldw = &lds[wave * 512];        // wave-uniform dest base

    auto stage = [&](int buf, int region, const unsigned short* s0,
                     const unsigned short* s1) {
        unsigned short* d = ldw + buf * 16384 + region * 4096;
        async16(s0, d);
        async16(s1, d + 2048);
    };

    // fragment read offsets (ushort units), swizzled
    int oA[4], oB[4];
#pragma unroll
    for (int i = 0; i < 4; i++) {
        const int r = wm * 64 + i * 16 + fr;
        oA[i] = r * 32 + ((quad ^ ((r >> 1) & 3)) << 3);
    }
#pragma unroll
    for (int j = 0; j < 4; j++) {
        const int r = wn * 64 + j * 16 + fr;
        oB[j] = r * 32 + ((quad ^ ((r >> 1) & 3)) << 3);
    }

    floatx4 acc[4][4];
#pragma unroll
    for (int i = 0; i < 4; i++)
#pragma unroll
        for (int j = 0; j < 4; j++) acc[i][j] = (floatx4){0.f, 0.f, 0.f, 0.f};

    // prologue (12 issued; vmcnt(8) -> first 4 = A_k0(0), B_k0(0) landed)
    stage(0, 0, aS0,      aS1);
    stage(0, 2, bS0,      bS1);
    stage(0, 1, aS0 + 32, aS1 + 32);
    stage(0, 3, bS0 + 32, bS1 + 32);
    stage(1, 0, aS0 + 64, aS1 + 64);
    stage(1, 2, bS0 + 64, bS1 + 64);
    asm volatile("s_waitcnt vmcnt(8)" ::: "memory");
    __builtin_amdgcn_s_barrier();
    __builtin_amdgcn_sched_barrier(0);

    bf16x8 af[2], bfr[4];
#pragma unroll 2
    for (int t = 0; t < 16; ++t) {
        const int cur = t & 1, nxt = cur ^ 1;
        const unsigned short* A0 = &lds[cur * 16384];
        const unsigned short* A1 = A0 + 4096;
        const unsigned short* B0 = A0 + 8192;
        const unsigned short* B1 = A0 + 12288;
        const int k1 = (t + 1) * 64, k2 = (t + 2) * 64;

        // ---------------- phase 0: kk=0, ihalf=0 ----------------
#pragma unroll
        for (int i = 0; i < 2; i++) af[i]  = *(const bf16x8*)&A0[oA[i]];
#pragma unroll
        for (int j = 0; j < 4; j++) bfr[j] = *(const bf16x8*)&B0[oB[j]];
        if (t + 1 < 16) stage(nxt, 1, aS0 + k1 + 32, aS1 + k1 + 32);
        __builtin_amdgcn_s_barrier();
        asm volatile("s_waitcnt lgkmcnt(0)" ::: "memory");
        __builtin_amdgcn_s_setprio(1);
#pragma unroll
        for (int i = 0; i < 2; i++)
#pragma unroll
            for (int j = 0; j < 4; j++)
                acc[i][j] = __builtin_amdgcn_mfma_f32_16x16x32_bf16(
                    af[i], bfr[j], acc[i][j], 0, 0, 0);
        __builtin_amdgcn_s_setprio(0);
        __builtin_amdgcn_s_barrier();
        __builtin_amdgcn_sched_barrier(0);

        // ---------------- phase 1: kk=0, ihalf=1 ----------------
#pragma unroll
        for (int i = 0; i < 2; i++) af[i] = *(const bf16x8*)&A0[oA[2 + i]];
        if (t + 1 < 16) stage(nxt, 3, bS0 + k1 + 32, bS1 + k1 + 32);
        if (t < 15) { asm volatile("s_waitcnt vmcnt(8)" ::: "memory"); }
        else        { asm volatile("s_waitcnt vmcnt(0)" ::: "memory"); }
        __builtin_amdgcn_s_barrier();
        asm volatile("s_waitcnt lgkmcnt(0)" ::: "memory");
        __builtin_amdgcn_s_setprio(1);
#pragma unroll
        for (int i = 0; i < 2; i++)
#pragma unroll
            for (int j = 0; j < 4; j++)
                acc[2 + i][j] = __builtin_amdgcn_mfma_f32_16x16x32_bf16(
                    af[i], bfr[j], acc[2 + i][j], 0, 0, 0);
        __builtin_amdgcn_s_setprio(0);
        __builtin_amdgcn_s_barrier();
        __builtin_amdgcn_sched_barrier(0);

        // ---------------- phase 2: kk=1, ihalf=0 ----------------
#pragma unroll
        for (int i = 0; i < 2; i++) af[i]  = *(const bf16x8*)&A1[oA[i]];
#pragma unroll
        for (int j = 0; j < 4; j++) bfr[j] = *(const bf16x8*)&B1[oB[j]];
        if (t + 2 < 16) stage(cur, 0, aS0 + k2, aS1 + k2);
        __builtin_amdgcn_s_barrier();
        asm volatile("s_waitcnt lgkmcnt(0)" ::: "memory");
        __builtin_amdgcn_s_setprio(1);
#pragma unroll
        for (int i = 0; i < 2; i++)
#pragma unroll
            for (int j = 0; j < 4; j++)
                acc[i][j] = __builtin_amdgcn_mfma_f32_16x16x32_bf16(
                    af[i], bfr[j], acc[i][j], 0, 0, 0);
        __builtin_amdgcn_s_setprio(0);
        __builtin_amdgcn_s_barrier();
        __builtin_amdgcn_sched_barrier(0);

        // ---------------- phase 3: kk=1, ihalf=1 ----------------
#pragma unroll
        for (int i = 0; i < 2; i++) af[i] = *(const bf16x8*)&A1[oA[2 + i]];
        if (t + 2 < 16) stage(cur, 2, bS0 + k2, bS1 + k2);
        if (t < 14) { asm volatile("s_waitcnt vmcnt(8)" ::: "memory"); }
        else        { asm volatile("s_waitcnt vmcnt(0)" ::: "memory"); }
        __builtin_amdgcn_s_barrier();
        asm volatile("s_waitcnt lgkmcnt(0)" ::: "memory");
        __builtin_amdgcn_s_setprio(1);
#pragma unroll
        for (int i = 0; i < 2; i++)
#pragma unroll
            for (int j = 0; j < 4; j++)
                acc[2 + i][j] = __builtin_amdgcn_mfma_f32_16x16x32_bf16(
                    af[i], bfr[j], acc[2 + i][j], 0, 0, 0);
        __builtin_amdgcn_s_setprio(0);
        __builtin_amdgcn_s_barrier();
        __builtin_amdgcn_sched_barrier(0);
    }

    // epilogue: fp32 store + bias
    const int rbase = quad * 4;
#pragma unroll
    for (int j = 0; j < 4; j++) {
        const int col = n0 + wn * 64 + j * 16 + fr;
        const float bz = bias[col];
#pragma unroll
        for (int i = 0; i < 4; i++) {
#pragma unroll
            for (int pr = 0; pr < 4; pr++) {
                const int row = m0 + wm * 64 + i * 16 + rbase + pr;
                out[(size_t)row * N_ + col] = acc[i][j][pr] + bz;
            }
        }
    }
}

// ---------------------------------------------------------------------------
extern "C" void kernel_launch(void* const* d_in, const int* in_sizes, int n_in,
                              void* d_out, int out_size, void* d_ws, size_t ws_size,
                              hipStream_t stream) {
    const float* x  = (const float*)d_in[0];
    const float* wq = (const float*)d_in[1];
    const float* bq = (const float*)d_in[2];
    const float* wk = (const float*)d_in[3];
    const float* bk = (const float*)d_in[4];
    const float* wv = (const float*)d_in[5];
    const float* bv = (const float*)d_in[6];
    const float* wc = (const float*)d_in[7];
    const float* bc = (const float*)d_in[8];
    float* out = (float*)d_out;

    // ws (ushort units): qb 0, kb 4M, vb 8M, yb 12M, xb 16M, wT 20M..24M (48 MB)
    unsigned short* ws  = (unsigned short*)d_ws;
    unsigned short* qb  = ws;                        // [B,H,T,HS] rope+scale
    unsigned short* kb  = ws + (size_t)4194304;      // [B,H,T,HS] rope
    unsigned short* vb  = ws + (size_t)8388608;      // [B,H,HS,T] (V^T)
    unsigned short* yb  = ws + (size_t)12582912;     // [B,T,C]
    unsigned short* xb  = ws + (size_t)16777216;     // x bf16 (dead after qkv)
    unsigned short* wT  = ws + (size_t)20971520;     // 4x bf16 [n][k]
    unsigned short* wcT = wT + ((size_t)3 << 20);
    unsigned short* Opart = xb;                      // split-K O' partials
    float*          Mpart = (float*)wT;              // split-K m,l partials
    float2*         tab   = (float2*)yb;             // RoPE table (dead before attn)

    prep_kernel<<<5184, 256, 0, stream>>>(x, wq, wk, wv, wc, xb, wT, tab);
    qkv_gemm<<<192, 512, 0, stream>>>(xb, wT, bq, bk, bv, tab, qb, kb, vb);
    attn_kernel<<<dim3(32, 48), 256, 0, stream>>>(qb, kb, vb, yb, Opart, Mpart);
    attn_combine<<<512, 256, 0, stream>>>(Opart, Mpart, yb);
    out_gemm<<<256, 256, 0, stream>>>(yb, wcT, bc, out);
}

// Round 10
// 187.129 us; speedup vs baseline: 1.0209x; 1.0042x over previous
//
#include <hip/hip_runtime.h>

#define B_  2
#define T_  2048
#define C_  1024
#define H_  16
#define HS_ 64
#define M_  4096
#define N_  1024
#define K_  1024

typedef float floatx4 __attribute__((ext_vector_type(4)));
typedef short bf16x8  __attribute__((ext_vector_type(8)));

__device__ __forceinline__ float bf2f(unsigned short u) {
    return __uint_as_float(((unsigned int)u) << 16);
}
__device__ __forceinline__ unsigned short f2bf(float f) {
    unsigned int u = __float_as_uint(f);
    return (unsigned short)((u + 0x7fffu + ((u >> 16) & 1u)) >> 16);
}
__device__ __forceinline__ unsigned int pack2(float a, float b) {
    return (unsigned int)f2bf(a) | ((unsigned int)f2bf(b) << 16);
}
// truncating bf16 pair pack: one v_perm_b32
__device__ __forceinline__ unsigned int pack2t(float a, float b) {
    return __builtin_amdgcn_perm(__float_as_uint(b), __float_as_uint(a), 0x07060302u);
}
// async global->LDS, 16B per lane; lds dest = wave-uniform base + lane*16
__device__ __forceinline__ void async16(const unsigned short* g, unsigned short* l) {
    __builtin_amdgcn_global_load_lds(
        (const __attribute__((address_space(1))) unsigned int*)g,
        (__attribute__((address_space(3))) unsigned int*)l, 16, 0, 0);
}

// ---------------------------------------------------------------------------
// Prep (merged): blocks 0..4095 convert x fp32->bf16; blocks 4096..5119
// transpose+convert weights; blocks 5120..5183 build the RoPE float2 table
// tab[t][f] = (cos, sin)(t * 10000^(-f/32)), t<2048, f<32 (512 KB, lives in
// the yb region which is dead until attn writes it).
// grid 5184, block 256.
// ---------------------------------------------------------------------------
__global__ __launch_bounds__(256) void prep_kernel(
    const float* __restrict__ x,
    const float* __restrict__ w0, const float* __restrict__ w1,
    const float* __restrict__ w2, const float* __restrict__ w3,
    unsigned short* __restrict__ xb, unsigned short* __restrict__ wTall,
    float2* __restrict__ tab)
{
    __shared__ float tile[64][65];
    const int bid = blockIdx.x;
    const int t = threadIdx.x;
    if (bid < 4096) {
        const size_t i = ((size_t)bid * 256 + t) * 4;
        const float4 v = *(const float4*)(x + i);
        ushort4 st;
        st.x = f2bf(v.x); st.y = f2bf(v.y); st.z = f2bf(v.z); st.w = f2bf(v.w);
        *(ushort4*)(xb + i) = st;
        return;
    }
    if (bid >= 5120) {                     // RoPE table: 64 blocks x 1024 entries
        const float nl = -0.41524101186279297f;   // -log2(10000)/32
        const int base = (bid - 5120) * 1024 + t * 4;
#pragma unroll
        for (int j = 0; j < 4; j++) {
            const int idx = base + j;
            const int tt = idx >> 5, f = idx & 31;
            float s, c;
            __sincosf((float)tt * exp2f((float)f * nl), &s, &c);
            tab[idx] = make_float2(c, s);
        }
        return;
    }
    const int zb = bid - 4096;
    const int z = zb >> 8, rem = zb & 255;
    const float* w = (z == 0) ? w0 : (z == 1) ? w1 : (z == 2) ? w2 : w3;
    unsigned short* wT = wTall + ((size_t)z << 20);
    const int n0 = (rem & 15) * 64, k0 = (rem >> 4) * 64;

    const int r = t >> 2, cq = (t & 3) * 16;
    const float4* src = (const float4*)(w + (size_t)(k0 + r) * N_ + n0 + cq);
    const float4 v0 = src[0], v1 = src[1], v2 = src[2], v3 = src[3];
    tile[r][cq+0]=v0.x; tile[r][cq+1]=v0.y; tile[r][cq+2]=v0.z; tile[r][cq+3]=v0.w;
    tile[r][cq+4]=v1.x; tile[r][cq+5]=v1.y; tile[r][cq+6]=v1.z; tile[r][cq+7]=v1.w;
    tile[r][cq+8]=v2.x; tile[r][cq+9]=v2.y; tile[r][cq+10]=v2.z; tile[r][cq+11]=v2.w;
    tile[r][cq+12]=v3.x; tile[r][cq+13]=v3.y; tile[r][cq+14]=v3.z; tile[r][cq+15]=v3.w;
    __syncthreads();

    const int rn = t >> 2, ck = (t & 3) * 16;
    unsigned int o[8];
#pragma unroll
    for (int ii = 0; ii < 8; ii++)
        o[ii] = pack2(tile[ck + 2*ii][rn], tile[ck + 2*ii + 1][rn]);
    unsigned short* dst = wT + (size_t)(n0 + rn) * K_ + k0 + ck;
    *(uint4*)dst       = make_uint4(o[0], o[1], o[2], o[3]);
    *(uint4*)(dst + 8) = make_uint4(o[4], o[5], o[6], o[7]);
}

// ---------------------------------------------------------------------------
// Kernel 1: fused QKV GEMM + RoPE epilogue.
// Single GEMM M=4096, N=3072, 256x256 tile, BK=64, 8 waves, 8-phase schedule
// with counted vmcnt (T3+T4), LDS chunk-XOR swizzle (T2), setprio (T5).
// Tail drain: vmcnt(0) when stages are predicated off (t>=14/15).
// RoPE epilogue reads the precomputed cos/sin table.
// NEW r10: (a) rectangular 4mb x 6nb per-XCD swizzle (L2 working set
// 7.3MB -> 5MB per XCD); (b) q/k stored in permuted column order
// col' = 4*(col&15) + col/16 so each thread's 4 RoPE outputs are one
// contiguous ushort4 (epilogue stores 128 x 2B -> 32 x 8B). attn is
// unchanged: K rows are staged whole (order-transparent) and Q/K fragments
// read identical col' slots, so QK^T pairs the same d's (permutation-
// invariant dot product). V and O keep true d order.
// grid 192, block 512.
// ---------------------------------------------------------------------------
__global__ __launch_bounds__(512, 2) void qkv_gemm(
    const unsigned short* __restrict__ xb, const unsigned short* __restrict__ wT,
    const float* __restrict__ bq, const float* __restrict__ bk,
    const float* __restrict__ bv, const float2* __restrict__ tab,
    unsigned short* __restrict__ qb, unsigned short* __restrict__ kb,
    unsigned short* __restrict__ vb)
{
    __shared__ unsigned short lds[65536];   // 128 KiB

    const int tid  = threadIdx.x;
    const int lane = tid & 63;
    const int wave = tid >> 6;

    // rectangular XCD swizzle: XCD x gets a 4mb x 6nb tile rectangle
    const int bid = blockIdx.x;
    const int xcd = bid & 7, idx = bid >> 3;       // dispatch round-robins XCDs
    const int mb  = (xcd >> 1) * 4 + (idx & 3);    // 0..15
    const int nb  = (xcd & 1) * 6 + (idx >> 2);    // 0..11
    const int m0  = mb * 256;
    const int n0g = nb * 256;

    const int wm = wave >> 2, wn = wave & 3;       // 2 x 4 wave grid
    const int fr = lane & 15, quad = lane >> 4;

    // staging: gload g covers LDS rows [g*128, g*128+128); thread t ->
    // row g*128+(t>>2), physical chunk t&3; source chunk = phys ^ ((row>>1)&3)
    const int r_s = tid >> 2;
    const int c_s = (tid & 3) ^ ((tid >> 3) & 3);
    const unsigned short* aS0 = xb + (size_t)(m0 + r_s) * 1024 + c_s * 8;
    const unsigned short* aS1 = aS0 + (size_t)128 * 1024;
    const unsigned short* bS0 = wT + (size_t)(n0g + r_s) * 1024 + c_s * 8;
    const unsigned short* bS1 = bS0 + (size_t)128 * 1024;
    unsigned short* ldw = &lds[wave * 512];        // wave-uniform dest base

    auto stage = [&](int buf, int region, const unsigned short* s0,
                     const unsigned short* s1) {
        unsigned short* d = ldw + buf * 32768 + region * 8192;
        async16(s0, d);
        async16(s1, d + 4096);
    };

    // fragment read offsets (ushort units), swizzled
    int oA[8], oB[4];
#pragma unroll
    for (int i = 0; i < 8; i++) {
        const int r = wm * 128 + i * 16 + fr;
        oA[i] = r * 32 + ((quad ^ ((r >> 1) & 3)) << 3);
    }
#pragma unroll
    for (int j = 0; j < 4; j++) {
        const int r = wn * 64 + j * 16 + fr;
        oB[j] = r * 32 + ((quad ^ ((r >> 1) & 3)) << 3);
    }

    floatx4 acc[8][4];
#pragma unroll
    for (int i = 0; i < 8; i++)
#pragma unroll
        for (int j = 0; j < 4; j++) acc[i][j] = (floatx4){0.f, 0.f, 0.f, 0.f};

    // prologue
    stage(0, 0, aS0,      aS1);
    stage(0, 2, bS0,      bS1);
    stage(0, 1, aS0 + 32, aS1 + 32);
    stage(0, 3, bS0 + 32, bS1 + 32);
    stage(1, 0, aS0 + 64, aS1 + 64);
    stage(1, 2, bS0 + 64, bS1 + 64);
    asm volatile("s_waitcnt vmcnt(8)" ::: "memory");   // k0(0) landed
    __builtin_amdgcn_s_barrier();
    __builtin_amdgcn_sched_barrier(0);

    bf16x8 af[4], bfr[4];
#pragma unroll 2
    for (int t = 0; t < 16; ++t) {
        const int cur = t & 1, nxt = cur ^ 1;
        const unsigned short* A0 = &lds[cur * 32768];
        const unsigned short* A1 = A0 + 8192;
        const unsigned short* B0 = A0 + 16384;
        const unsigned short* B1 = A0 + 24576;
        const int k1 = (t + 1) * 64, k2 = (t + 2) * 64;

        // ---------------- phase 0: kk=0, ihalf=0 ----------------
#pragma unroll
        for (int i = 0; i < 4; i++) af[i]  = *(const bf16x8*)&A0[oA[i]];
#pragma unroll
        for (int j = 0; j < 4; j++) bfr[j] = *(const bf16x8*)&B0[oB[j]];
        if (t + 1 < 16) stage(nxt, 1, aS0 + k1 + 32, aS1 + k1 + 32);
        __builtin_amdgcn_s_barrier();
        asm volatile("s_waitcnt lgkmcnt(0)" ::: "memory");
        __builtin_amdgcn_s_setprio(1);
#pragma unroll
        for (int i = 0; i < 4; i++)
#pragma unroll
            for (int j = 0; j < 4; j++)
                acc[i][j] = __builtin_amdgcn_mfma_f32_16x16x32_bf16(
                    af[i], bfr[j], acc[i][j], 0, 0, 0);
        __builtin_amdgcn_s_setprio(0);
        __builtin_amdgcn_s_barrier();
        __builtin_amdgcn_sched_barrier(0);

        // ---------------- phase 1: kk=0, ihalf=1 ----------------
#pragma unroll
        for (int i = 0; i < 4; i++) af[i] = *(const bf16x8*)&A0[oA[4 + i]];
        if (t + 1 < 16) stage(nxt, 3, bS0 + k1 + 32, bS1 + k1 + 32);
        if (t < 15) { asm volatile("s_waitcnt vmcnt(8)" ::: "memory"); }
        else        { asm volatile("s_waitcnt vmcnt(0)" ::: "memory"); }
        __builtin_amdgcn_s_barrier();
        asm volatile("s_waitcnt lgkmcnt(0)" ::: "memory");
        __builtin_amdgcn_s_setprio(1);
#pragma unroll
        for (int i = 0; i < 4; i++)
#pragma unroll
            for (int j = 0; j < 4; j++)
                acc[4 + i][j] = __builtin_amdgcn_mfma_f32_16x16x32_bf16(
                    af[i], bfr[j], acc[4 + i][j], 0, 0, 0);
        __builtin_amdgcn_s_setprio(0);
        __builtin_amdgcn_s_barrier();
        __builtin_amdgcn_sched_barrier(0);

        // ---------------- phase 2: kk=1, ihalf=0 ----------------
#pragma unroll
        for (int i = 0; i < 4; i++) af[i]  = *(const bf16x8*)&A1[oA[i]];
#pragma unroll
        for (int j = 0; j < 4; j++) bfr[j] = *(const bf16x8*)&B1[oB[j]];
        if (t + 2 < 16) stage(cur, 0, aS0 + k2, aS1 + k2);
        __builtin_amdgcn_s_barrier();
        asm volatile("s_waitcnt lgkmcnt(0)" ::: "memory");
        __builtin_amdgcn_s_setprio(1);
#pragma unroll
        for (int i = 0; i < 4; i++)
#pragma unroll
            for (int j = 0; j < 4; j++)
                acc[i][j] = __builtin_amdgcn_mfma_f32_16x16x32_bf16(
                    af[i], bfr[j], acc[i][j], 0, 0, 0);
        __builtin_amdgcn_s_setprio(0);
        __builtin_amdgcn_s_barrier();
        __builtin_amdgcn_sched_barrier(0);

        // ---------------- phase 3: kk=1, ihalf=1 ----------------
#pragma unroll
        for (int i = 0; i < 4; i++) af[i] = *(const bf16x8*)&A1[oA[4 + i]];
        if (t + 2 < 16) stage(cur, 2, bS0 + k2, bS1 + k2);
        if (t < 14) { asm volatile("s_waitcnt vmcnt(8)" ::: "memory"); }
        else        { asm volatile("s_waitcnt vmcnt(0)" ::: "memory"); }
        __builtin_amdgcn_s_barrier();
        asm volatile("s_waitcnt lgkmcnt(0)" ::: "memory");
        __builtin_amdgcn_s_setprio(1);
#pragma unroll
        for (int i = 0; i < 4; i++)
#pragma unroll
            for (int j = 0; j < 4; j++)
                acc[4 + i][j] = __builtin_amdgcn_mfma_f32_16x16x32_bf16(
                    af[i], bfr[j], acc[4 + i][j], 0, 0, 0);
        __builtin_amdgcn_s_setprio(0);
        __builtin_amdgcn_s_barrier();
        __builtin_amdgcn_sched_barrier(0);
    }

    // ---- epilogue: RoPE for q/k (table-driven, permuted-col ushort4
    // stores), transposed store for V ----
    const int p = nb >> 2;                       // 0=q, 1=k, 2=v (block-uniform)
    const int colbase = (nb & 3) * 256 + wn * 64;
    const int h = colbase >> 6;
    const int rb = quad * 4;
    const float* bias = (p == 0) ? bq : (p == 1) ? bk : bv;

    if (p == 2) {    // V transposed: [B,H,HS,T] (true d order)
#pragma unroll
        for (int j = 0; j < 4; j++) {
            const int d = j * 16 + fr;
            const float bz = bias[colbase + d];
#pragma unroll
            for (int i = 0; i < 8; i++) {
                const int row0 = m0 + wm * 128 + i * 16 + rb;
                const int bb = row0 >> 11, tt = row0 & 2047;
                ushort4 st;
                st.x = f2bf(acc[i][j][0] + bz);
                st.y = f2bf(acc[i][j][1] + bz);
                st.z = f2bf(acc[i][j][2] + bz);
                st.w = f2bf(acc[i][j][3] + bz);
                *(ushort4*)&vb[((size_t)(bb * H_ + h) * HS_ + d) * T_ + tt] = st;
            }
        }
    } else {
        // q/k stored at col' = 4*(col&15) + col/16: thread's 4 values are
        // contiguous. Q and K share the permutation -> QK^T unchanged.
        unsigned short* out = (p == 0) ? qb : kb;
        const float qsc = (p == 0) ? 0.18033688011111772f : 1.0f;  // 0.125*log2(e)
        const float bz0 = bias[colbase + fr];
        const float bz1 = bias[colbase + 16 + fr];
        const float bz2 = bias[colbase + 32 + fr];
        const float bz3 = bias[colbase + 48 + fr];
#pragma unroll
        for (int i = 0; i < 8; i++) {
#pragma unroll
            for (int pr = 0; pr < 4; pr++) {
                const int row = m0 + wm * 128 + i * 16 + rb + pr;
                const int bb = row >> 11, tt = row & 2047;
                const float2 cs0 = tab[tt * 32 + fr];
                const float2 cs1 = tab[tt * 32 + fr + 16];
                const float c0 = cs0.x, s0 = cs0.y;
                const float c1 = cs1.x, s1 = cs1.y;
                const float v0 = acc[i][0][pr] + bz0;
                const float v1 = acc[i][1][pr] + bz1;
                const float v2 = acc[i][2][pr] + bz2;
                const float v3 = acc[i][3][pr] + bz3;
                ushort4 st;
                st.x = f2bf((v0 * c0 - v2 * s0) * qsc);   // col fr      -> 4fr+0
                st.y = f2bf((v1 * c1 - v3 * s1) * qsc);   // col fr+16   -> 4fr+1
                st.z = f2bf((v2 * c0 + v0 * s0) * qsc);   // col fr+32   -> 4fr+2
                st.w = f2bf((v3 * c1 + v1 * s1) * qsc);   // col fr+48   -> 4fr+3
                *(ushort4*)&out[((size_t)(bb * H_ + h) * T_ + tt) * HS_ + fr * 4] = st;
            }
        }
    }
}

// ---------------------------------------------------------------------------
// Kernel 3: MFMA flash attention, split-K flash-decoding.
// Double-buffered K/V (prefetch regs at top, LDS write at iter end, off the
// critical path). Defer-max (T13) with shfl ONLY in rescale branch; per-lane
// l partial (cross-lane l-reduce once at end); setprio (T5); tree reductions.
// q/k arrive in permuted col order (see qkv) — transparent here: K rows are
// staged whole, and Q/K fragments read identical col' slots.
// grid (32, 48), block 256.  [r6 structure — best measured: 48.1 us]
// ---------------------------------------------------------------------------
__global__ __launch_bounds__(256) void attn_kernel(
    const unsigned short* __restrict__ qb, const unsigned short* __restrict__ kb,
    const unsigned short* __restrict__ vt, unsigned short* __restrict__ yb,
    unsigned short* __restrict__ Opart, float* __restrict__ Mpart)
{
    __shared__ unsigned short Ks[2][64 * 64];
    __shared__ unsigned short Vs[2][64 * 64];
    __shared__ unsigned short Ps[4][16 * 64];

    const int bh = blockIdx.x;
    const int b = bh >> 4, h = bh & 15;
    const int s = 47 - (int)blockIdx.y;          // LPT: biggest first
    int qt, ktlo, kthi, half;
    bool split;
    if (s < 16) { qt = s; ktlo = 0; kthi = qt; half = 0; split = false; }
    else {
        const int idx = s - 16;
        qt = 16 + (idx >> 1); half = idx & 1;
        const int nf = (qt + 2) >> 1;
        ktlo = half ? nf : 0;
        kthi = half ? qt : nf - 1;
        split = true;
    }
    const int r0 = qt * 64;
    const int tid  = threadIdx.x;
    const int lane = tid & 63;
    const int wave = tid >> 6;
    const int l4   = lane & 15;
    const int quad = lane >> 4;

    const int qrow_g = r0 + wave * 16 + l4;

    bf16x8 qf[2];
    {
        const unsigned short* qp = qb + ((size_t)bh * T_ + qrow_g) * HS_ + quad * 8;
        qf[0] = *(const bf16x8*)(qp);
        qf[1] = *(const bf16x8*)(qp + 32);
    }

    floatx4 o[4];
#pragma unroll
    for (int g = 0; g < 4; g++) o[g] = (floatx4){0.f, 0.f, 0.f, 0.f};
    float m = -1e30f, l = 0.f;        // l is a PER-LANE partial (reduced at end)

    const int srow = tid >> 2;
    const int sc16 = (tid & 3) * 16;
    const int ssw  = (srow & 7) * 8;
    const int psw  = (l4 & 7) * 8;

    const unsigned short* kp = kb + ((size_t)bh * T_ + srow) * HS_ + sc16;
    const unsigned short* vp = vt + ((size_t)(bh * 64 + srow)) * T_ + sc16;

    uint4 rk0 = *(const uint4*)(kp + (size_t)ktlo * 64 * HS_);
    uint4 rk1 = *(const uint4*)(kp + (size_t)ktlo * 64 * HS_ + 8);
    uint4 rv0 = *(const uint4*)(vp + ktlo * 64);
    uint4 rv1 = *(const uint4*)(vp + ktlo * 64 + 8);
    *(uint4*)&Ks[0][srow * 64 + ( sc16      ^ ssw)] = rk0;
    *(uint4*)&Ks[0][srow * 64 + ((sc16 + 8) ^ ssw)] = rk1;
    *(uint4*)&Vs[0][srow * 64 + ( sc16      ^ ssw)] = rv0;
    *(uint4*)&Vs[0][srow * 64 + ((sc16 + 8) ^ ssw)] = rv1;

    for (int kt = ktlo; kt <= kthi; kt++) {
        const int cur = (kt - ktlo) & 1;
        if (kt < kthi) {                               // issue next-tile loads
            const unsigned short* kpn = kp + (size_t)(kt + 1) * (64 * HS_);
            const unsigned short* vpn = vp + (kt + 1) * 64;
            rk0 = *(const uint4*)kpn;
            rk1 = *(const uint4*)(kpn + 8);
            rv0 = *(const uint4*)vpn;
            rv1 = *(const uint4*)(vpn + 8);
        }
        __syncthreads();

        floatx4 sf[4];
        __builtin_amdgcn_s_setprio(1);
#pragma unroll
        for (int mg = 0; mg < 4; mg++) {
            const int key = mg * 16 + l4;
            const int ksw = (key & 7) * 8;
            const bf16x8 a0 = *(const bf16x8*)&Ks[cur][key * 64 + ( (quad * 8)       ^ ksw)];
            const bf16x8 a1 = *(const bf16x8*)&Ks[cur][key * 64 + (((quad * 8) + 32) ^ ksw)];
            floatx4 z = (floatx4){0.f, 0.f, 0.f, 0.f};
            z = __builtin_amdgcn_mfma_f32_16x16x32_bf16(a0, qf[0], z, 0, 0, 0);
            z = __builtin_amdgcn_mfma_f32_16x16x32_bf16(a1, qf[1], z, 0, 0, 0);
            sf[mg] = z;
        }
        __builtin_amdgcn_s_setprio(0);

        if (kt == qt) {
#pragma unroll
            for (int mg = 0; mg < 4; mg++)
#pragma unroll
                for (int r = 0; r < 4; r++)
                    if (kt * 64 + 16 * mg + quad * 4 + r > qrow_g)
                        sf[mg][r] = -1e30f;
        }

        // per-lane tree max (no cross-lane in common path)
        float mx[4];
#pragma unroll
        for (int mg = 0; mg < 4; mg++)
            mx[mg] = fmaxf(fmaxf(sf[mg][0], sf[mg][1]),
                           fmaxf(sf[mg][2], sf[mg][3]));
        float tm = fmaxf(fmaxf(mx[0], mx[1]), fmaxf(mx[2], mx[3]));

        // defer-max (T13): rescale only when some lane grew by > 8 (log2 units)
        if (!__all(tm <= m + 8.f)) {
            tm = fmaxf(tm, __shfl_xor(tm, 16));        // row-uniform max
            tm = fmaxf(tm, __shfl_xor(tm, 32));
            const float mnew  = fmaxf(m, tm);
            const float alpha = __builtin_amdgcn_exp2f(m - mnew);
            l *= alpha;
#pragma unroll
            for (int g = 0; g < 4; g++) o[g] = o[g] * alpha;
            m = mnew;
        }

        float p[4][4];
        float psg[4];
#pragma unroll
        for (int mg = 0; mg < 4; mg++) {
#pragma unroll
            for (int r = 0; r < 4; r++)
                p[mg][r] = __builtin_amdgcn_exp2f(sf[mg][r] - m);
            psg[mg] = (p[mg][0] + p[mg][1]) + (p[mg][2] + p[mg][3]);
        }
        l += (psg[0] + psg[1]) + (psg[2] + psg[3]);    // per-lane partial

#pragma unroll
        for (int mg = 0; mg < 4; mg++) {
            const int kb4 = 16 * mg + quad * 4;
            const int off = ((kb4 & ~7) ^ psw) | (kb4 & 7);
            uint2 w;
            w.x = pack2t(p[mg][0], p[mg][1]);
            w.y = pack2t(p[mg][2], p[mg][3]);
            *(uint2*)&Ps[wave][l4 * 64 + off] = w;
        }

        const bf16x8 pf0 = *(const bf16x8*)&Ps[wave][l4 * 64 + ( (quad * 8)       ^ psw)];
        const bf16x8 pf1 = *(const bf16x8*)&Ps[wave][l4 * 64 + (((quad * 8) + 32) ^ psw)];
        __builtin_amdgcn_s_setprio(1);
#pragma unroll
        for (int g = 0; g < 4; g++) {
            const int vd  = g * 16 + l4;
            const int vsw = (vd & 7) * 8;
            const bf16x8 va0 = *(const bf16x8*)&Vs[cur][vd * 64 + ( (quad * 8)       ^ vsw)];
            const bf16x8 va1 = *(const bf16x8*)&Vs[cur][vd * 64 + (((quad * 8) + 32) ^ vsw)];
            o[g] = __builtin_amdgcn_mfma_f32_16x16x32_bf16(va0, pf0, o[g], 0, 0, 0);
            o[g] = __builtin_amdgcn_mfma_f32_16x16x32_bf16(va1, pf1, o[g], 0, 0, 0);
        }
        __builtin_amdgcn_s_setprio(0);

        if (kt < kthi) {                               // stage next tile (off path)
            const int nxt = cur ^ 1;
            *(uint4*)&Ks[nxt][srow * 64 + ( sc16      ^ ssw)] = rk0;
            *(uint4*)&Ks[nxt][srow * 64 + ((sc16 + 8) ^ ssw)] = rk1;
            *(uint4*)&Vs[nxt][srow * 64 + ( sc16      ^ ssw)] = rv0;
            *(uint4*)&Vs[nxt][srow * 64 + ((sc16 + 8) ^ ssw)] = rv1;
        }
    }

    // row-reduce the per-lane l partial once
    l += __shfl_xor(l, 16);
    l += __shfl_xor(l, 32);

    if (!split) {
        const float invl = 1.f / l;
        unsigned short* yrow = yb + ((size_t)(b * T_ + qrow_g) * H_ + h) * HS_;
#pragma unroll
        for (int g = 0; g < 4; g++) {
            ushort4 st;
            st.x = f2bf(o[g][0] * invl);
            st.y = f2bf(o[g][1] * invl);
            st.z = f2bf(o[g][2] * invl);
            st.w = f2bf(o[g][3] * invl);
            *(ushort4*)&yrow[16 * g + quad * 4] = st;
        }
    } else {
        const int u  = (bh * 16 + (qt - 16)) * 2 + half;
        const int rl = wave * 16 + l4;
        unsigned short* Op = Opart + (size_t)u * 4096 + rl * 64;
#pragma unroll
        for (int g = 0; g < 4; g++) {
            ushort4 st;
            st.x = f2bf(o[g][0]);
            st.y = f2bf(o[g][1]);
            st.z = f2bf(o[g][2]);
            st.w = f2bf(o[g][3]);
            *(ushort4*)&Op[16 * g + quad * 4] = st;
        }
        if (quad == 0) {
            float* ml = Mpart + (size_t)u * 128;
            ml[rl]      = m;
            ml[64 + rl] = l;
        }
    }
}

// ---------------------------------------------------------------------------
// Kernel 3b: merge split-K partials. grid 512, block 256.
// ---------------------------------------------------------------------------
__global__ __launch_bounds__(256) void attn_combine(
    const unsigned short* __restrict__ Opart, const float* __restrict__ Mpart,
    unsigned short* __restrict__ yb)
{
    const int u  = blockIdx.x;
    const int bh = u >> 4, qt = 16 + (u & 15);
    const int b = bh >> 4, h = bh & 15;
    const int t = threadIdx.x;
    const int r = t >> 2, c = (t & 3) * 16;

    const float* ml1 = Mpart + (size_t)(u * 2) * 128;
    const float* ml2 = ml1 + 128;
    const float m1 = ml1[r], l1 = ml1[64 + r];
    const float m2 = ml2[r], l2 = ml2[64 + r];
    const float M  = fmaxf(m1, m2);
    const float w1 = __builtin_amdgcn_exp2f(m1 - M);
    const float w2 = __builtin_amdgcn_exp2f(m2 - M);
    const float inv = 1.f / (l1 * w1 + l2 * w2);
    const float a1 = w1 * inv, a2 = w2 * inv;

    const unsigned short* O1 = Opart + (size_t)(u * 2)     * 4096 + r * 64 + c;
    const unsigned short* O2 = Opart + (size_t)(u * 2 + 1) * 4096 + r * 64 + c;
    unsigned short* yrow = yb + ((size_t)(b * T_ + qt * 64 + r) * H_ + h) * HS_ + c;

#pragma unroll
    for (int j = 0; j < 2; j++) {
        const uint4 u1 = *(const uint4*)(O1 + 8 * j);
        const uint4 u2 = *(const uint4*)(O2 + 8 * j);
        const unsigned int a[4] = {u1.x, u1.y, u1.z, u1.w};
        const unsigned int d[4] = {u2.x, u2.y, u2.z, u2.w};
        unsigned int ov[4];
#pragma unroll
        for (int q = 0; q < 4; q++) {
            const float y0 = bf2f((unsigned short)(a[q] & 0xffff)) * a1
                           + bf2f((unsigned short)(d[q] & 0xffff)) * a2;
            const float y1 = bf2f((unsigned short)(a[q] >> 16)) * a1
                           + bf2f((unsigned short)(d[q] >> 16)) * a2;
            ov[q] = pack2(y0, y1);
        }
        *(uint4*)(yrow + 8 * j) = make_uint4(ov[0], ov[1], ov[2], ov[3]);
    }
}

// ---------------------------------------------------------------------------
// Kernel 4: output projection, 8-phase port of the qkv schedule.
// 128x128 tile, BK=64, 4 waves (each 64x64), 64 KiB LDS (2buf x 4 regions x
// 8KB), counted vmcnt(8) with tail drain, chunk-XOR swizzle both-sides,
// XCD swizzle. grid 256 (= 32 mt x 8 nt), block 256.
// ---------------------------------------------------------------------------
__global__ __launch_bounds__(256, 2) void out_gemm(
    const unsigned short* __restrict__ A, const unsigned short* __restrict__ wcT,
    const float* __restrict__ bias, float* __restrict__ out)
{
    __shared__ unsigned short lds[32768];   // 64 KiB

    const int tid  = threadIdx.x;
    const int lane = tid & 63;
    const int wave = tid >> 6;

    // XCD swizzle: 256 % 8 == 0; consecutive swz share nt (B panel) per XCD
    const int bid = blockIdx.x;
    const int swz = (bid & 7) * 32 + (bid >> 3);
    const int nt  = swz >> 5;       // 0..7
    const int mt  = swz & 31;       // 0..31
    const int m0  = mt * 128;
    const int n0  = nt * 128;

    const int wm = wave >> 1, wn = wave & 1;       // 2 x 2 wave grid
    const int fr = lane & 15, quad = lane >> 4;

    // staging: gload g covers region rows [g*64, g*64+64); thread t ->
    // row g*64+(t>>2), physical chunk t&3; source chunk = phys ^ ((row>>1)&3)
    const int r_s = tid >> 2;                       // 0..63
    const int c_s = (tid & 3) ^ ((tid >> 3) & 3);
    const unsigned short* aS0 = A   + (size_t)(m0 + r_s) * 1024 + c_s * 8;
    const unsigned short* aS1 = aS0 + (size_t)64 * 1024;
    const unsigned short* bS0 = wcT + (size_t)(n0 + r_s) * 1024 + c_s * 8;
    const unsigned short* bS1 = bS0 + (size_t)64 * 1024;
    unsigned short* ldw = &lds[wave * 512];        // wave-uniform dest base

    auto stage = [&](int buf, int region, const unsigned short* s0,
                     const unsigned short* s1) {
        unsigned short* d = ldw + buf * 16384 + region * 4096;
        async16(s0, d);
        async16(s1, d + 2048);
    };

    // fragment read offsets (ushort units), swizzled
    int oA[4], oB[4];
#pragma unroll
    for (int i = 0; i < 4; i++) {
        const int r = wm * 64 + i * 16 + fr;
        oA[i] = r * 32 + ((quad ^ ((r >> 1) & 3)) << 3);
    }
#pragma unroll
    for (int j = 0; j < 4; j++) {
        const int r = wn * 64 + j * 16 + fr;
        oB[j] = r * 32 + ((quad ^ ((r >> 1) & 3)) << 3);
    }

    floatx4 acc[4][4];
#pragma unroll
    for (int i = 0; i < 4; i++)
#pragma unroll
        for (int j = 0; j < 4; j++) acc[i][j] = (floatx4){0.f, 0.f, 0.f, 0.f};

    // prologue (12 issued; vmcnt(8) -> first 4 = A_k0(0), B_k0(0) landed)
    stage(0, 0, aS0,      aS1);
    stage(0, 2, bS0,      bS1);
    stage(0, 1, aS0 + 32, aS1 + 32);
    stage(0, 3, bS0 + 32, bS1 + 32);
    stage(1, 0, aS0 + 64, aS1 + 64);
    stage(1, 2, bS0 + 64, bS1 + 64);
    asm volatile("s_waitcnt vmcnt(8)" ::: "memory");
    __builtin_amdgcn_s_barrier();
    __builtin_amdgcn_sched_barrier(0);

    bf16x8 af[2], bfr[4];
#pragma unroll 2
    for (int t = 0; t < 16; ++t) {
        const int cur = t & 1, nxt = cur ^ 1;
        const unsigned short* A0 = &lds[cur * 16384];
        const unsigned short* A1 = A0 + 4096;
        const unsigned short* B0 = A0 + 8192;
        const unsigned short* B1 = A0 + 12288;
        const int k1 = (t + 1) * 64, k2 = (t + 2) * 64;

        // ---------------- phase 0: kk=0, ihalf=0 ----------------
#pragma unroll
        for (int i = 0; i < 2; i++) af[i]  = *(const bf16x8*)&A0[oA[i]];
#pragma unroll
        for (int j = 0; j < 4; j++) bfr[j] = *(const bf16x8*)&B0[oB[j]];
        if (t + 1 < 16) stage(nxt, 1, aS0 + k1 + 32, aS1 + k1 + 32);
        __builtin_amdgcn_s_barrier();
        asm volatile("s_waitcnt lgkmcnt(0)" ::: "memory");
        __builtin_amdgcn_s_setprio(1);
#pragma unroll
        for (int i = 0; i < 2; i++)
#pragma unroll
            for (int j = 0; j < 4; j++)
                acc[i][j] = __builtin_amdgcn_mfma_f32_16x16x32_bf16(
                    af[i], bfr[j], acc[i][j], 0, 0, 0);
        __builtin_amdgcn_s_setprio(0);
        __builtin_amdgcn_s_barrier();
        __builtin_amdgcn_sched_barrier(0);

        // ---------------- phase 1: kk=0, ihalf=1 ----------------
#pragma unroll
        for (int i = 0; i < 2; i++) af[i] = *(const bf16x8*)&A0[oA[2 + i]];
        if (t + 1 < 16) stage(nxt, 3, bS0 + k1 + 32, bS1 + k1 + 32);
        if (t < 15) { asm volatile("s_waitcnt vmcnt(8)" ::: "memory"); }
        else        { asm volatile("s_waitcnt vmcnt(0)" ::: "memory"); }
        __builtin_amdgcn_s_barrier();
        asm volatile("s_waitcnt lgkmcnt(0)" ::: "memory");
        __builtin_amdgcn_s_setprio(1);
#pragma unroll
        for (int i = 0; i < 2; i++)
#pragma unroll
            for (int j = 0; j < 4; j++)
                acc[2 + i][j] = __builtin_amdgcn_mfma_f32_16x16x32_bf16(
                    af[i], bfr[j], acc[2 + i][j], 0, 0, 0);
        __builtin_amdgcn_s_setprio(0);
        __builtin_amdgcn_s_barrier();
        __builtin_amdgcn_sched_barrier(0);

        // ---------------- phase 2: kk=1, ihalf=0 ----------------
#pragma unroll
        for (int i = 0; i < 2; i++) af[i]  = *(const bf16x8*)&A1[oA[i]];
#pragma unroll
        for (int j = 0; j < 4; j++) bfr[j] = *(const bf16x8*)&B1[oB[j]];
        if (t + 2 < 16) stage(cur, 0, aS0 + k2, aS1 + k2);
        __builtin_amdgcn_s_barrier();
        asm volatile("s_waitcnt lgkmcnt(0)" ::: "memory");
        __builtin_amdgcn_s_setprio(1);
#pragma unroll
        for (int i = 0; i < 2; i++)
#pragma unroll
            for (int j = 0; j < 4; j++)
                acc[i][j] = __builtin_amdgcn_mfma_f32_16x16x32_bf16(
                    af[i], bfr[j], acc[i][j], 0, 0, 0);
        __builtin_amdgcn_s_setprio(0);
        __builtin_amdgcn_s_barrier();
        __builtin_amdgcn_sched_barrier(0);

        // ---------------- phase 3: kk=1, ihalf=1 ----------------
#pragma unroll
        for (int i = 0; i < 2; i++) af[i] = *(const bf16x8*)&A1[oA[2 + i]];
        if (t + 2 < 16) stage(cur, 2, bS0 + k2, bS1 + k2);
        if (t < 14) { asm volatile("s_waitcnt vmcnt(8)" ::: "memory"); }
        else        { asm volatile("s_waitcnt vmcnt(0)" ::: "memory"); }
        __builtin_amdgcn_s_barrier();
        asm volatile("s_waitcnt lgkmcnt(0)" ::: "memory");
        __builtin_amdgcn_s_setprio(1);
#pragma unroll
        for (int i = 0; i < 2; i++)
#pragma unroll
            for (int j = 0; j < 4; j++)
                acc[2 + i][j] = __builtin_amdgcn_mfma_f32_16x16x32_bf16(
                    af[i], bfr[j], acc[2 + i][j], 0, 0, 0);
        __builtin_amdgcn_s_setprio(0);
        __builtin_amdgcn_s_barrier();
        __builtin_amdgcn_sched_barrier(0);
    }

    // epilogue: fp32 store + bias
    const int rbase = quad * 4;
#pragma unroll
    for (int j = 0; j < 4; j++) {
        const int col = n0 + wn * 64 + j * 16 + fr;
        const float bz = bias[col];
#pragma unroll
        for (int i = 0; i < 4; i++) {
#pragma unroll
            for (int pr = 0; pr < 4; pr++) {
                const int row = m0 + wm * 64 + i * 16 + rbase + pr;
                out[(size_t)row * N_ + col] = acc[i][j][pr] + bz;
            }
        }
    }
}

// ---------------------------------------------------------------------------
extern "C" void kernel_launch(void* const* d_in, const int* in_sizes, int n_in,
                              void* d_out, int out_size, void* d_ws, size_t ws_size,
                              hipStream_t stream) {
    const float* x  = (const float*)d_in[0];
    const float* wq = (const float*)d_in[1];
    const float* bq = (const float*)d_in[2];
    const float* wk = (const float*)d_in[3];
    const float* bk = (const float*)d_in[4];
    const float* wv = (const float*)d_in[5];
    const float* bv = (const float*)d_in[6];
    const float* wc = (const float*)d_in[7];
    const float* bc = (const float*)d_in[8];
    float* out = (float*)d_out;

    // ws (ushort units): qb 0, kb 4M, vb 8M, yb 12M, xb 16M, wT 20M..24M (48 MB)
    unsigned short* ws  = (unsigned short*)d_ws;
    unsigned short* qb  = ws;                        // [B,H,T,HS] rope+scale (permuted cols)
    unsigned short* kb  = ws + (size_t)4194304;      // [B,H,T,HS] rope (permuted cols)
    unsigned short* vb  = ws + (size_t)8388608;      // [B,H,HS,T] (V^T)
    unsigned short* yb  = ws + (size_t)12582912;     // [B,T,C]
    unsigned short* xb  = ws + (size_t)16777216;     // x bf16 (dead after qkv)
    unsigned short* wT  = ws + (size_t)20971520;     // 4x bf16 [n][k]
    unsigned short* wcT = wT + ((size_t)3 << 20);
    unsigned short* Opart = xb;                      // split-K O' partials
    float*          Mpart = (float*)wT;              // split-K m,l partials
    float2*         tab   = (float2*)yb;             // RoPE table (dead before attn)

    prep_kernel<<<5184, 256, 0, stream>>>(x, wq, wk, wv, wc, xb, wT, tab);
    qkv_gemm<<<192, 512, 0, stream>>>(xb, wT, bq, bk, bv, tab, qb, kb, vb);
    attn_kernel<<<dim3(32, 48), 256, 0, stream>>>(qb, kb, vb, yb, Opart, Mpart);
    attn_combine<<<512, 256, 0, stream>>>(Opart, Mpart, yb);
    out_gemm<<<256, 256, 0, stream>>>(yb, wcT, bc, out);
}